// Round 4
// baseline (1023.083 us; speedup 1.0000x reference)
//
#include <hip/hip_runtime.h>

typedef unsigned short u16;
typedef __attribute__((ext_vector_type(8))) short bf16x8;
typedef __attribute__((ext_vector_type(8))) unsigned short u16x8;
typedef __attribute__((ext_vector_type(4))) float f32x4;

__device__ __forceinline__ u16 f2bf(float f) {
  unsigned u = __builtin_bit_cast(unsigned, f);
  u += 0x7fffu + ((u >> 16) & 1u);
  return (u16)(u >> 16);
}
__device__ __forceinline__ float bf2f(u16 h) {
  unsigned u = ((unsigned)h) << 16;
  return __builtin_bit_cast(float, u);
}

#define NB 2048
#define NF 100
#define NE 64
#define NO 256
#define OCH 64
#define EMB_ST 68
#define EMBT_ST 136
#define GAW_ST 136

#define GLOAD16(gsrc, ldst)                                                        \
  __builtin_amdgcn_global_load_lds(                                                \
      (const __attribute__((address_space(1))) unsigned int*)(gsrc),               \
      (__attribute__((address_space(3))) unsigned int*)(ldst), 16, 0, 0)

// ---------------- prep: M[o][e] = 0.0625 * sum_k query[o,k]*Wb[k,e] ----------------
__global__ void k_prep_M(const float* __restrict__ wb, const float* __restrict__ q,
                         u16* __restrict__ mt) {
  int idx = blockIdx.x * 256 + threadIdx.x;   // 16384 = 256*64
  int o = idx >> 6, e = idx & 63;
  float s = 0.f;
  for (int k = 0; k < 64; ++k) s = fmaf(q[o * 64 + k], wb[k * 64 + e], s);
  mt[idx] = f2bf(s * 0.0625f);   // folds DK^-0.5 (0.125) and (alpha-1) (0.5)
}

// ---------------- f32 -> bf16 conversion ----------------
__global__ void k_cvt(const float* __restrict__ in, u16* __restrict__ out, int n) {
  int i4 = (blockIdx.x * 256 + threadIdx.x) * 4;
  if (i4 >= n) return;
  float4 v = *(const float4*)(in + i4);
  ushort4 o;
  o.x = f2bf(v.x); o.y = f2bf(v.y); o.z = f2bf(v.z); o.w = f2bf(v.w);
  *(ushort4*)(out + i4) = o;
}

// ------- f32 -> bf16 with per-k scale: w0'[n][k] = bf16(w0[n][k] * scl[k>>6]) -------
// (arm-BN scale folded into W0; all arm-BN/mlp_b0 bias terms cancel in the
//  next batch-BN, so no bias path is needed at all.)
__global__ void k_cvt_w0s(const float* __restrict__ in, const float* __restrict__ scl,
                          u16* __restrict__ out) {
  size_t i4 = ((size_t)blockIdx.x * 256 + threadIdx.x) * 4;
  int o = (int)((i4 >> 6) & 255);
  float sc = scl[o];
  float4 v = *(const float4*)(in + i4);
  ushort4 u;
  u.x = f2bf(v.x * sc); u.y = f2bf(v.y * sc);
  u.z = f2bf(v.z * sc); u.w = f2bf(v.w * sc);
  *(ushort4*)(out + i4) = u;
}

// ------- fused gather + (per-o-chunk: gates GEMM + entmax + arm GEMM + expm1) -------
__global__ __launch_bounds__(256) void k_mega(
    const int* __restrict__ ids, const float* __restrict__ vals,
    const float* __restrict__ etab, const u16* __restrict__ mt,
    const float* __restrict__ att, u16* __restrict__ tbuf) {
  __shared__ u16 s_emb[112][EMB_ST];     // [f][e], rows 100..111 zero
  __shared__ u16 s_embT[64][EMBT_ST];    // [e][f], cols 100..135 zero
  __shared__ u16 s_gaw[64][GAW_ST];      // phase1-2: gates; phase2-3: p*att (aliased)

  const int tid = threadIdx.x;
  const int lane = tid & 63;
  const int wid = tid >> 6;
  const int b = blockIdx.x;

  // phase 0: gather emb = emb_table[ids]*clip(v)  (once per b)
  for (int f = wid; f < NF; f += 4) {
    int id = ids[b * NF + f];
    float v = vals[b * NF + f];
    v = fminf(fmaxf(v, 0.001f), 1.0f);
    float ev = etab[(size_t)id * NE + lane] * v;
    u16 bf = f2bf(ev);
    s_emb[f][lane] = bf;
    s_embT[lane][f] = bf;
  }
  for (int i = tid; i < 12 * 64; i += 256) s_emb[100 + (i >> 6)][i & 63] = 0;
  for (int i = tid; i < 64 * 36; i += 256) s_embT[i / 36][100 + i % 36] = 0;
  __syncthreads();

  for (int oc = 0; oc < 4; ++oc) {
    const int obase = oc * OCH;
    bf16x8 amt[2];
#pragma unroll
    for (int kh = 0; kh < 2; ++kh)
      amt[kh] = *(const bf16x8*)(mt + ((obase + wid * 16 + (lane & 15)) * 64 +
                                       kh * 32 + ((lane >> 4) * 8)));

    // phase 1: gates[o][f] = M[o,:]·emb[f,:]
#pragma unroll
    for (int ft = 0; ft < 7; ++ft) {
      f32x4 acc = {0.f, 0.f, 0.f, 0.f};
#pragma unroll
      for (int kh = 0; kh < 2; ++kh) {
        bf16x8 bfr = *(const bf16x8*)&s_emb[ft * 16 + (lane & 15)][kh * 32 + ((lane >> 4) * 8)];
        acc = __builtin_amdgcn_mfma_f32_16x16x32_bf16(amt[kh], bfr, acc, 0, 0, 0);
      }
      int fc = ft * 16 + (lane & 15);
      if (fc < NF) {
#pragma unroll
        for (int i = 0; i < 4; ++i)
          s_gaw[wid * 16 + ((lane >> 4) * 4) + i][fc] = f2bf(acc[i]);
      }
    }
    __syncthreads();

    // phase 2: entmax(alpha=1.5); quad (4 lanes) per o-row.
    // 6 bisection steps bracket tau to 0.9/64=0.014; 4 Newton steps on the
    // convex decreasing f(tau)=sum max(x-tau,0)^2-1 finish to ~1e-9
    // (monotone from the f>=0 side, quadratic convergence).
    {
      const int q = tid & 3;
      const int r = tid >> 2;
      const int og = obase + r;
      float x[25];
#pragma unroll
      for (int j = 0; j < 25; ++j) x[j] = bf2f(s_gaw[r][q * 25 + j]);
      float mx = x[0];
#pragma unroll
      for (int j = 1; j < 25; ++j) mx = fmaxf(mx, x[j]);
      mx = fmaxf(mx, __shfl_xor(mx, 1));
      mx = fmaxf(mx, __shfl_xor(mx, 2));
      float tau = mx - 1.0f, dm = 0.9f;   // tau_hi - tau_lo = 1 - (1/100)^0.5
#pragma unroll
      for (int it = 0; it < 6; ++it) {
        dm *= 0.5f;
        float tm = tau + dm;
        float s = 0.f;
#pragma unroll
        for (int j = 0; j < 25; ++j) { float d = fmaxf(x[j] - tm, 0.f); s = fmaf(d, d, s); }
        s += __shfl_xor(s, 1);
        s += __shfl_xor(s, 2);
        if (s >= 1.0f) tau = tm;
      }
#pragma unroll
      for (int it = 0; it < 4; ++it) {
        float s = 0.f, sd = 0.f;
#pragma unroll
        for (int j = 0; j < 25; ++j) {
          float d = fmaxf(x[j] - tau, 0.f);
          s = fmaf(d, d, s);
          sd += d;
        }
        s += __shfl_xor(s, 1);
        s += __shfl_xor(s, 2);
        sd += __shfl_xor(sd, 1);
        sd += __shfl_xor(sd, 2);
        tau += (s - 1.0f) / (2.0f * sd + 1e-30f);
      }
      float s = 0.f;
#pragma unroll
      for (int j = 0; j < 25; ++j) {
        float d = fmaxf(x[j] - tau, 0.f);
        float p = d * d;
        x[j] = p;
        s += p;
      }
      s += __shfl_xor(s, 1);
      s += __shfl_xor(s, 2);
      float rs = 1.0f / s;
      __syncthreads();   // all gate reads done before aliased aw writes
#pragma unroll
      for (int j = 0; j < 25; ++j) {
        int f = q * 25 + j;
        s_gaw[r][f] = f2bf(x[j] * rs * att[og * NF + f]);
      }
#pragma unroll
      for (int j = 0; j < 9; ++j) s_gaw[r][100 + q * 9 + j] = 0;
    }
    __syncthreads();

    // phase 3: arm[o][e] = sum_f aw[o][f]*emb[f][e];  store t = exp(arm)-1
    f32x4 acc[4] = {};
#pragma unroll
    for (int h = 0; h < 4; ++h) {
      bf16x8 afr = *(const bf16x8*)&s_gaw[wid * 16 + (lane & 15)][h * 32 + ((lane >> 4) * 8)];
#pragma unroll
      for (int et = 0; et < 4; ++et) {
        bf16x8 bfr = *(const bf16x8*)&s_embT[et * 16 + (lane & 15)][h * 32 + ((lane >> 4) * 8)];
        acc[et] = __builtin_amdgcn_mfma_f32_16x16x32_bf16(afr, bfr, acc[et], 0, 0, 0);
      }
    }
    size_t orow = (size_t)b * NO + obase + wid * 16 + ((lane >> 4) * 4);
#pragma unroll
    for (int et = 0; et < 4; ++et) {
      int e = et * 16 + (lane & 15);
#pragma unroll
      for (int i = 0; i < 4; ++i)
        tbuf[(orow + i) * 64 + e] = f2bf(__expf(acc[et][i]) - 1.0f);
    }
    __syncthreads();   // protect s_gaw for next oc
  }
}

// ---------------- per-o BN scale over (b,e): scl = g*rsqrt(var+eps) ----------------
__global__ void k_stats_o(const u16* __restrict__ t, const float* __restrict__ g,
                          float* __restrict__ scl) {
  int tid = threadIdx.x;
  int o = blockIdx.x;
  int e = tid & 63, gq = tid >> 6;
  float s = 0.f, s2 = 0.f;
  for (int b = gq; b < NB; b += 4) {
    float v = bf2f(t[((size_t)b * NO + o) * 64 + e]);
    s += v;
    s2 = fmaf(v, v, s2);
  }
  __shared__ float red[2][256];
  red[0][tid] = s; red[1][tid] = s2;
  __syncthreads();
  for (int st = 128; st >= 1; st >>= 1) {
    if (tid < st) { red[0][tid] += red[0][tid + st]; red[1][tid] += red[1][tid + st]; }
    __syncthreads();
  }
  if (tid == 0) {
    float N = (float)(NB * 64);
    float m = red[0][0] / N;
    float var = red[1][0] / N - m * m;
    scl[o] = g[o] * rsqrtf(var + 1e-5f);
  }
}

// ---- bf16 GEMM, C[m][n] = sum_k A[m][k]*B[n][k] (B^T layout), split-K ----
// m97 structure: linear [128][64] LDS, global_load_lds width=16 staging,
// 2-barrier K-loop, 4 waves, 4x4 16x16x32 acc per wave.
__global__ __launch_bounds__(256) void k_gemm(const u16* __restrict__ A,
                                              const u16* __restrict__ B,
                                              float* __restrict__ C,
                                              int M, int N, int K, int ksz) {
  __shared__ u16 sA[128][64];
  __shared__ u16 sB[128][64];
  const int tid = threadIdx.x, lane = tid & 63, wid = tid >> 6;
  const int wr = wid >> 1, wc = wid & 1;
  const int m0 = blockIdx.x * 128, n0 = blockIdx.y * 128;
  const int k0 = blockIdx.z * ksz;
  C += (size_t)blockIdx.z * ((size_t)M * N);
  f32x4 acc[4][4];
#pragma unroll
  for (int mi = 0; mi < 4; ++mi)
#pragma unroll
    for (int ni = 0; ni < 4; ++ni) acc[mi][ni] = (f32x4){0.f, 0.f, 0.f, 0.f};

  const int lrow = lane >> 3;    // 0..7
  const int lch = lane & 7;      // 16B chunk in row
  const u16* gA = A + (size_t)(m0 + wid * 32 + lrow) * K + k0 + lch * 8;
  const u16* gB = B + (size_t)(n0 + wid * 32 + lrow) * K + k0 + lch * 8;
  u16* lA = &sA[wid * 32][0];    // wave-uniform LDS base
  u16* lB = &sB[wid * 32][0];

  const int nkt = ksz / 64;
  for (int kt = 0; kt < nkt; ++kt) {
#pragma unroll
    for (int i = 0; i < 4; ++i) {
      GLOAD16(gA + (size_t)i * 8 * K, lA + i * 512);
      GLOAD16(gB + (size_t)i * 8 * K, lB + i * 512);
    }
    gA += 64; gB += 64;
    __syncthreads();
#pragma unroll
    for (int kh = 0; kh < 2; ++kh) {
      bf16x8 af[4], bfv[4];
#pragma unroll
      for (int i = 0; i < 4; ++i) {
        af[i]  = *(const bf16x8*)&sA[wr * 64 + i * 16 + (lane & 15)][kh * 32 + ((lane >> 4) * 8)];
        bfv[i] = *(const bf16x8*)&sB[wc * 64 + i * 16 + (lane & 15)][kh * 32 + ((lane >> 4) * 8)];
      }
#pragma unroll
      for (int mi = 0; mi < 4; ++mi)
#pragma unroll
        for (int ni = 0; ni < 4; ++ni)
          acc[mi][ni] = __builtin_amdgcn_mfma_f32_16x16x32_bf16(af[mi], bfv[ni], acc[mi][ni], 0, 0, 0);
    }
    __syncthreads();
  }
#pragma unroll
  for (int mi = 0; mi < 4; ++mi) {
    int m = m0 + wr * 64 + mi * 16 + ((lane >> 4) * 4);
#pragma unroll
    for (int ni = 0; ni < 4; ++ni) {
      int n = n0 + wc * 64 + ni * 16 + (lane & 15);
#pragma unroll
      for (int i = 0; i < 4; ++i) C[(size_t)(m + i) * N + n] = acc[mi][ni][i];
    }
  }
}

// ---------------- sum 8 split-K partials: r0 = sum_z c01[z] ----------------
__global__ void k_reduce8(const float* __restrict__ c, float* __restrict__ r) {
  size_t i4 = ((size_t)blockIdx.x * 256 + threadIdx.x) * 4;
  float4 s = *(const float4*)(c + i4);
#pragma unroll
  for (int z = 1; z < 8; ++z) {
    float4 v = *(const float4*)(c + (size_t)z * 2048 * 1024 + i4);
    s.x += v.x; s.y += v.y; s.z += v.z; s.w += v.w;
  }
  *(float4*)(r + i4) = s;
}

// ------- per-column BN stats over batch (summing nparts split-K partials) -------
__global__ void k_stats_cols(const float* __restrict__ c0, int nparts,
                             const float* __restrict__ g, const float* __restrict__ be,
                             float* __restrict__ scl, float* __restrict__ bia,
                             int rows, int cols) {
  int tid = threadIdx.x;
  int col = blockIdx.x * 64 + (tid & 63);
  int gq = tid >> 6;
  const size_t pstride = (size_t)rows * cols;
  float s = 0.f, s2 = 0.f;
  for (int r = gq; r < rows; r += 4) {
    float v = c0[(size_t)r * cols + col];
    for (int p = 1; p < nparts; ++p) v += c0[p * pstride + (size_t)r * cols + col];
    s += v;
    s2 = fmaf(v, v, s2);
  }
  __shared__ float red[2][256];
  red[0][tid] = s; red[1][tid] = s2;
  __syncthreads();
  if (tid < 64) {
    s  = red[0][tid] + red[0][tid + 64] + red[0][tid + 128] + red[0][tid + 192];
    s2 = red[1][tid] + red[1][tid + 64] + red[1][tid + 128] + red[1][tid + 192];
    float m = s / rows;
    float var = s2 / rows - m * m;
    float inv = rsqrtf(var + 1e-5f);
    scl[col] = g[col] * inv;
    bia[col] = be[col] - g[col] * inv * m;
  }
}

// ---------------- a1 = bf16(relu(r0*scl + bia)) ----------------
__global__ void k_applyA1(const float* __restrict__ c0,
                          const float* __restrict__ scl, const float* __restrict__ bia,
                          u16* __restrict__ a1) {
  size_t i4 = ((size_t)blockIdx.x * 256 + threadIdx.x) * 4;
  int n = (int)(i4 & 1023);
  float4 v0 = *(const float4*)(c0 + i4);
  ushort4 o;
  o.x = f2bf(fmaxf(fmaf(v0.x, scl[n + 0], bia[n + 0]), 0.f));
  o.y = f2bf(fmaxf(fmaf(v0.y, scl[n + 1], bia[n + 1]), 0.f));
  o.z = f2bf(fmaxf(fmaf(v0.z, scl[n + 2], bia[n + 2]), 0.f));
  o.w = f2bf(fmaxf(fmaf(v0.w, scl[n + 3], bia[n + 3]), 0.f));
  *(ushort4*)(a1 + i4) = o;
}

// -------- y[b] = out_b + sum_n relu((sum_p h_p)*scl+bia)*out_w[n], 4 partials --------
__global__ void k_final(const float* __restrict__ h, const float* __restrict__ scl,
                        const float* __restrict__ bia, const float* __restrict__ ow,
                        const float* __restrict__ ob, float* __restrict__ y) {
  int lane = threadIdx.x & 63, wid = threadIdx.x >> 6;
  int row = blockIdx.x * 4 + wid;
  const float* hr = h + (size_t)row * 1024;
  const size_t ps = (size_t)2048 * 1024;
  float part = 0.f;
#pragma unroll
  for (int j = 0; j < 16; ++j) {
    int n = j * 64 + lane;
    float v = hr[n] + hr[ps + n] + hr[2 * ps + n] + hr[3 * ps + n];
    v = fmaxf(fmaf(v, scl[n], bia[n]), 0.f);
    part = fmaf(v, ow[n], part);
  }
#pragma unroll
  for (int off = 32; off >= 1; off >>= 1) part += __shfl_xor(part, off);
  if (lane == 0) y[row] = part + ob[0];
}

extern "C" void kernel_launch(void* const* d_in, const int* in_sizes, int n_in,
                              void* d_out, int out_size, void* d_ws, size_t ws_size,
                              hipStream_t stream) {
  const int*   ids   = (const int*)d_in[0];
  const float* vals  = (const float*)d_in[1];
  const float* etab  = (const float*)d_in[2];
  const float* wb    = (const float*)d_in[3];
  const float* query = (const float*)d_in[4];
  const float* att   = (const float*)d_in[5];
  const float* bng   = (const float*)d_in[6];
  const float* w0    = (const float*)d_in[8];
  const float* g0    = (const float*)d_in[10];
  const float* be0   = (const float*)d_in[11];
  const float* w1    = (const float*)d_in[12];
  const float* g1    = (const float*)d_in[14];
  const float* be1   = (const float*)d_in[15];
  const float* outw  = (const float*)d_in[16];
  const float* outb  = (const float*)d_in[17];
  float* y = (float*)d_out;

  // workspace layout (peak ~199.3 MB, unchanged):
  //   [0, 32K)            mt
  //   [32K, 33.59M)       w0bf (32MB, pre-scaled by arm-BN scl)
  //   [33.59M, 35.68M)    w1bf (2MB)
  //   [35.68M, 102.79M)   tbuf (64MB bf16)       -- alive through gemm0 (A operand)
  //   [102.79M, 166.90M)  c01 (8x8MB f32)        -- gemm0 partials; dead after reduce8
  //   [102.79M, 136.33M)  h1 (4x8MB f32)         -- overlays dead c01, gemm1 partials
  //   [169.90M, 178.29M)  r0 (8MB f32)
  //   [178.29M, 182.48M)  a1 (4MB bf16)
  //   [199.26M, ...)      BN scale/bias scalars
  char* ws = (char*)d_ws;
  u16*   mt   = (u16*)(ws + 0);
  u16*   w0bf = (u16*)(ws + 32768ull);
  u16*   w1bf = (u16*)(ws + 33587200ull);
  u16*   tbuf = (u16*)(ws + 35684352ull);
  float* c01  = (float*)(ws + 102793216ull);
  float* h1   = (float*)(ws + 102793216ull);
  float* r0   = (float*)(ws + 169902080ull);
  u16*   a1   = (u16*)(ws + 178290688ull);
  float* sclA = (float*)(ws + 199262208ull);
  float* scl1 = (float*)(ws + 199264256ull);
  float* bia1 = (float*)(ws + 199268352ull);
  float* scl2 = (float*)(ws + 199272448ull);
  float* bia2 = (float*)(ws + 199276544ull);

  k_prep_M<<<64, 256, 0, stream>>>(wb, query, mt);
  k_cvt<<<1024, 256, 0, stream>>>(w1, w1bf, 1024 * 1024);
  k_mega<<<2048, 256, 0, stream>>>(ids, vals, etab, mt, att, tbuf);
  k_stats_o<<<256, 256, 0, stream>>>(tbuf, bng, sclA);
  k_cvt_w0s<<<16384, 256, 0, stream>>>(w0, sclA, w0bf);
  // gemm0: A = tbuf directly (arm-BN scale folded into w0bf; biases cancel
  // in the following batch-BN). split-K=8 -> 1024 blocks = 4/CU.
  k_gemm<<<dim3(16, 8, 8), 256, 0, stream>>>(tbuf, w0bf, c01, 2048, 1024, 16384, 2048);
  k_reduce8<<<2048, 256, 0, stream>>>(c01, r0);
  k_stats_cols<<<16, 256, 0, stream>>>(r0, 1, g0, be0, scl1, bia1, 2048, 1024);
  k_applyA1<<<2048, 256, 0, stream>>>(r0, scl1, bia1, a1);
  // gemm1: split-K=4 -> 512 blocks = 2/CU; partials overlay dead c01.
  k_gemm<<<dim3(16, 8, 4), 256, 0, stream>>>(a1, w1bf, h1, 2048, 1024, 1024, 256);
  k_stats_cols<<<16, 256, 0, stream>>>(h1, 4, g1, be1, scl2, bia2, 2048, 1024);
  k_final<<<512, 256, 0, stream>>>(h1, scl2, bia2, outw, outb, y);
}

// Round 5
// 310.247 us; speedup vs baseline: 3.2976x; 3.2976x over previous
//
#include <hip/hip_runtime.h>

typedef unsigned short u16;
typedef __attribute__((ext_vector_type(8))) short bf16x8;
typedef __attribute__((ext_vector_type(8))) unsigned short u16x8;
typedef __attribute__((ext_vector_type(4))) float f32x4;

__device__ __forceinline__ u16 f2bf(float f) {
  unsigned u = __builtin_bit_cast(unsigned, f);
  u += 0x7fffu + ((u >> 16) & 1u);
  return (u16)(u >> 16);
}
__device__ __forceinline__ float bf2f(u16 h) {
  unsigned u = ((unsigned)h) << 16;
  return __builtin_bit_cast(float, u);
}

#define NB 2048
#define NF 100
#define NE 64
#define NO 256
#define OCH 64
#define EMB_ST 68
#define EMBT_ST 136
#define GAW_ST 136

#define GLOAD16(gsrc, ldst)                                                        \
  __builtin_amdgcn_global_load_lds(                                                \
      (const __attribute__((address_space(1))) unsigned int*)(gsrc),               \
      (__attribute__((address_space(3))) unsigned int*)(ldst), 16, 0, 0)

// ---------------- prep: M[o][e] = 0.0625 * sum_k query[o,k]*Wb[k,e] ----------------
__global__ void k_prep_M(const float* __restrict__ wb, const float* __restrict__ q,
                         u16* __restrict__ mt) {
  int idx = blockIdx.x * 256 + threadIdx.x;   // 16384 = 256*64
  int o = idx >> 6, e = idx & 63;
  float s = 0.f;
  for (int k = 0; k < 64; ++k) s = fmaf(q[o * 64 + k], wb[k * 64 + e], s);
  mt[idx] = f2bf(s * 0.0625f);   // folds DK^-0.5 (0.125) and (alpha-1) (0.5)
}

// ---------------- f32 -> bf16 conversion ----------------
__global__ void k_cvt(const float* __restrict__ in, u16* __restrict__ out, int n) {
  int i4 = (blockIdx.x * 256 + threadIdx.x) * 4;
  if (i4 >= n) return;
  float4 v = *(const float4*)(in + i4);
  ushort4 o;
  o.x = f2bf(v.x); o.y = f2bf(v.y); o.z = f2bf(v.z); o.w = f2bf(v.w);
  *(ushort4*)(out + i4) = o;
}

// ------- f32 -> bf16 with per-k scale: w0'[n][k] = bf16(w0[n][k] * scl[k>>6]) -------
__global__ void k_cvt_w0s(const float* __restrict__ in, const float* __restrict__ scl,
                          u16* __restrict__ out) {
  size_t i4 = ((size_t)blockIdx.x * 256 + threadIdx.x) * 4;
  int o = (int)((i4 >> 6) & 255);
  float sc = scl[o];
  float4 v = *(const float4*)(in + i4);
  ushort4 u;
  u.x = f2bf(v.x * sc); u.y = f2bf(v.y * sc);
  u.z = f2bf(v.z * sc); u.w = f2bf(v.w * sc);
  *(ushort4*)(out + i4) = u;
}

// ------- fused gather + (per-o-chunk: gates GEMM + entmax + arm GEMM + exp-1) -------
__global__ __launch_bounds__(256) void k_mega(
    const int* __restrict__ ids, const float* __restrict__ vals,
    const float* __restrict__ etab, const u16* __restrict__ mt,
    const float* __restrict__ att, u16* __restrict__ tbuf) {
  __shared__ u16 s_emb[112][EMB_ST];     // [f][e], rows 100..111 zero
  __shared__ u16 s_embT[64][EMBT_ST];    // [e][f], cols 100..135 zero
  __shared__ u16 s_gaw[64][GAW_ST];      // phase1-2: gates; phase2-3: p*att (aliased)

  const int tid = threadIdx.x;
  const int lane = tid & 63;
  const int wid = tid >> 6;
  const int b = blockIdx.x;

  // phase 0: gather emb = emb_table[ids]*clip(v)  (once per b)
  for (int f = wid; f < NF; f += 4) {
    int id = ids[b * NF + f];
    float v = vals[b * NF + f];
    v = fminf(fmaxf(v, 0.001f), 1.0f);
    float ev = etab[(size_t)id * NE + lane] * v;
    u16 bf = f2bf(ev);
    s_emb[f][lane] = bf;
    s_embT[lane][f] = bf;
  }
  for (int i = tid; i < 12 * 64; i += 256) s_emb[100 + (i >> 6)][i & 63] = 0;
  for (int i = tid; i < 64 * 36; i += 256) s_embT[i / 36][100 + i % 36] = 0;
  __syncthreads();

  for (int oc = 0; oc < 4; ++oc) {
    const int obase = oc * OCH;
    bf16x8 amt[2];
#pragma unroll
    for (int kh = 0; kh < 2; ++kh)
      amt[kh] = *(const bf16x8*)(mt + ((obase + wid * 16 + (lane & 15)) * 64 +
                                       kh * 32 + ((lane >> 4) * 8)));

    // phase 1: gates[o][f] = M[o,:]·emb[f,:]
#pragma unroll
    for (int ft = 0; ft < 7; ++ft) {
      f32x4 acc = {0.f, 0.f, 0.f, 0.f};
#pragma unroll
      for (int kh = 0; kh < 2; ++kh) {
        bf16x8 bfr = *(const bf16x8*)&s_emb[ft * 16 + (lane & 15)][kh * 32 + ((lane >> 4) * 8)];
        acc = __builtin_amdgcn_mfma_f32_16x16x32_bf16(amt[kh], bfr, acc, 0, 0, 0);
      }
      int fc = ft * 16 + (lane & 15);
      if (fc < NF) {
#pragma unroll
        for (int i = 0; i < 4; ++i)
          s_gaw[wid * 16 + ((lane >> 4) * 4) + i][fc] = f2bf(acc[i]);
      }
    }
    __syncthreads();

    // phase 2: entmax(alpha=1.5); quad (4 lanes) per o-row.
    // 6 bisection steps bracket tau; 4 Newton steps (monotone from f>=0 side,
    // quadratic) finish to ~1e-9.
    {
      const int q = tid & 3;
      const int r = tid >> 2;
      const int og = obase + r;
      float x[25];
#pragma unroll
      for (int j = 0; j < 25; ++j) x[j] = bf2f(s_gaw[r][q * 25 + j]);
      float mx = x[0];
#pragma unroll
      for (int j = 1; j < 25; ++j) mx = fmaxf(mx, x[j]);
      mx = fmaxf(mx, __shfl_xor(mx, 1));
      mx = fmaxf(mx, __shfl_xor(mx, 2));
      float tau = mx - 1.0f, dm = 0.9f;   // tau_hi - tau_lo = 1 - (1/100)^0.5
#pragma unroll
      for (int it = 0; it < 6; ++it) {
        dm *= 0.5f;
        float tm = tau + dm;
        float s = 0.f;
#pragma unroll
        for (int j = 0; j < 25; ++j) { float d = fmaxf(x[j] - tm, 0.f); s = fmaf(d, d, s); }
        s += __shfl_xor(s, 1);
        s += __shfl_xor(s, 2);
        if (s >= 1.0f) tau = tm;
      }
#pragma unroll
      for (int it = 0; it < 4; ++it) {
        float s = 0.f, sd = 0.f;
#pragma unroll
        for (int j = 0; j < 25; ++j) {
          float d = fmaxf(x[j] - tau, 0.f);
          s = fmaf(d, d, s);
          sd += d;
        }
        s += __shfl_xor(s, 1);
        s += __shfl_xor(s, 2);
        sd += __shfl_xor(sd, 1);
        sd += __shfl_xor(sd, 2);
        tau += (s - 1.0f) / (2.0f * sd + 1e-30f);
      }
      float s = 0.f;
#pragma unroll
      for (int j = 0; j < 25; ++j) {
        float d = fmaxf(x[j] - tau, 0.f);
        float p = d * d;
        x[j] = p;
        s += p;
      }
      s += __shfl_xor(s, 1);
      s += __shfl_xor(s, 2);
      float rs = 1.0f / s;
      __syncthreads();   // all gate reads done before aliased aw writes
#pragma unroll
      for (int j = 0; j < 25; ++j) {
        int f = q * 25 + j;
        s_gaw[r][f] = f2bf(x[j] * rs * att[og * NF + f]);
      }
#pragma unroll
      for (int j = 0; j < 9; ++j) s_gaw[r][100 + q * 9 + j] = 0;
    }
    __syncthreads();

    // phase 3: arm[o][e] = sum_f aw[o][f]*emb[f][e];  store t = exp(arm)-1
    f32x4 acc[4] = {};
#pragma unroll
    for (int h = 0; h < 4; ++h) {
      bf16x8 afr = *(const bf16x8*)&s_gaw[wid * 16 + (lane & 15)][h * 32 + ((lane >> 4) * 8)];
#pragma unroll
      for (int et = 0; et < 4; ++et) {
        bf16x8 bfr = *(const bf16x8*)&s_embT[et * 16 + (lane & 15)][h * 32 + ((lane >> 4) * 8)];
        acc[et] = __builtin_amdgcn_mfma_f32_16x16x32_bf16(afr, bfr, acc[et], 0, 0, 0);
      }
    }
    size_t orow = (size_t)b * NO + obase + wid * 16 + ((lane >> 4) * 4);
#pragma unroll
    for (int et = 0; et < 4; ++et) {
      int e = et * 16 + (lane & 15);
#pragma unroll
      for (int i = 0; i < 4; ++i)
        tbuf[(orow + i) * 64 + e] = f2bf(__expf(acc[et][i]) - 1.0f);
    }
    __syncthreads();   // protect s_gaw for next oc
  }
}

// ------- per-o BN stats stage A: partial (s,s2) over a 256-batch slice -------
__global__ void k_stats_o_part(const u16* __restrict__ t, float* __restrict__ pstat) {
  const int o = blockIdx.x, bs = blockIdx.y;
  const int e = threadIdx.x & 63, bt = threadIdx.x >> 6;
  float s = 0.f, s2 = 0.f;
  for (int b = bs * 256 + bt; b < bs * 256 + 256; b += 4) {
    float v = bf2f(t[((size_t)b * NO + o) * 64 + e]);
    s += v;
    s2 = fmaf(v, v, s2);
  }
  __shared__ float red[2][256];
  red[0][threadIdx.x] = s; red[1][threadIdx.x] = s2;
  __syncthreads();
  for (int st = 128; st >= 1; st >>= 1) {
    if (threadIdx.x < st) {
      red[0][threadIdx.x] += red[0][threadIdx.x + st];
      red[1][threadIdx.x] += red[1][threadIdx.x + st];
    }
    __syncthreads();
  }
  if (threadIdx.x == 0) {
    pstat[((size_t)bs * NO + o) * 2] = red[0][0];
    pstat[((size_t)bs * NO + o) * 2 + 1] = red[1][0];
  }
}

// ------- per-o BN stats stage B: scl = g*rsqrt(var+eps) -------
__global__ void k_stats_o_fin(const float* __restrict__ pstat, const float* __restrict__ g,
                              float* __restrict__ scl) {
  int o = threadIdx.x;
  float s = 0.f, s2 = 0.f;
#pragma unroll
  for (int p = 0; p < 8; ++p) {
    s  += pstat[((size_t)p * NO + o) * 2];
    s2 += pstat[((size_t)p * NO + o) * 2 + 1];
  }
  float invN = 1.0f / (float)(NB * 64);
  float m = s * invN;
  float var = s2 * invN - m * m;
  scl[o] = g[o] * rsqrtf(var + 1e-5f);
}

// ---- bf16 GEMM, C[m][n] = sum_k A[m][k]*B[n][k] (B^T layout), split-K ----
__global__ __launch_bounds__(256) void k_gemm(const u16* __restrict__ A,
                                              const u16* __restrict__ B,
                                              float* __restrict__ C,
                                              int M, int N, int K, int ksz) {
  __shared__ u16 sA[128][64];
  __shared__ u16 sB[128][64];
  const int tid = threadIdx.x, lane = tid & 63, wid = tid >> 6;
  const int wr = wid >> 1, wc = wid & 1;
  const int m0 = blockIdx.x * 128, n0 = blockIdx.y * 128;
  const int k0 = blockIdx.z * ksz;
  C += (size_t)blockIdx.z * ((size_t)M * N);
  f32x4 acc[4][4];
#pragma unroll
  for (int mi = 0; mi < 4; ++mi)
#pragma unroll
    for (int ni = 0; ni < 4; ++ni) acc[mi][ni] = (f32x4){0.f, 0.f, 0.f, 0.f};

  const int lrow = lane >> 3;    // 0..7
  const int lch = lane & 7;      // 16B chunk in row
  const u16* gA = A + (size_t)(m0 + wid * 32 + lrow) * K + k0 + lch * 8;
  const u16* gB = B + (size_t)(n0 + wid * 32 + lrow) * K + k0 + lch * 8;
  u16* lA = &sA[wid * 32][0];    // wave-uniform LDS base
  u16* lB = &sB[wid * 32][0];

  const int nkt = ksz / 64;
  for (int kt = 0; kt < nkt; ++kt) {
#pragma unroll
    for (int i = 0; i < 4; ++i) {
      GLOAD16(gA + (size_t)i * 8 * K, lA + i * 512);
      GLOAD16(gB + (size_t)i * 8 * K, lB + i * 512);
    }
    gA += 64; gB += 64;
    __syncthreads();
#pragma unroll
    for (int kh = 0; kh < 2; ++kh) {
      bf16x8 af[4], bfv[4];
#pragma unroll
      for (int i = 0; i < 4; ++i) {
        af[i]  = *(const bf16x8*)&sA[wr * 64 + i * 16 + (lane & 15)][kh * 32 + ((lane >> 4) * 8)];
        bfv[i] = *(const bf16x8*)&sB[wc * 64 + i * 16 + (lane & 15)][kh * 32 + ((lane >> 4) * 8)];
      }
#pragma unroll
      for (int mi = 0; mi < 4; ++mi)
#pragma unroll
        for (int ni = 0; ni < 4; ++ni)
          acc[mi][ni] = __builtin_amdgcn_mfma_f32_16x16x32_bf16(af[mi], bfv[ni], acc[mi][ni], 0, 0, 0);
    }
    __syncthreads();
  }
#pragma unroll
  for (int mi = 0; mi < 4; ++mi) {
    int m = m0 + wr * 64 + mi * 16 + ((lane >> 4) * 4);
#pragma unroll
    for (int ni = 0; ni < 4; ++ni) {
      int n = n0 + wc * 64 + ni * 16 + (lane & 15);
#pragma unroll
      for (int i = 0; i < 4; ++i) C[(size_t)(m + i) * N + n] = acc[mi][ni][i];
    }
  }
}

// ---- fused: r = sum of NP split-K partials  +  per-(rowgroup,col) BN partial stats ----
// grid (16 colgroups, 32 rowgroups) = 512 blocks; 256B/wave coalesced column access.
template <int NP>
__global__ void k_red_stats(const float* __restrict__ c, float* __restrict__ r,
                            float* __restrict__ pstat) {
  const int col = blockIdx.x * 64 + (threadIdx.x & 63);
  const int rt = threadIdx.x >> 6;
  const int rg = blockIdx.y;
  const size_t ps = (size_t)NB * 1024;
  float s = 0.f, s2 = 0.f;
  for (int rr = rt; rr < 64; rr += 4) {
    size_t idx = (size_t)(rg * 64 + rr) * 1024 + col;
    float v = c[idx];
#pragma unroll
    for (int p = 1; p < NP; ++p) v += c[p * ps + idx];
    r[idx] = v;
    s += v;
    s2 = fmaf(v, v, s2);
  }
  __shared__ float red[2][256];
  red[0][threadIdx.x] = s; red[1][threadIdx.x] = s2;
  __syncthreads();
  if (threadIdx.x < 64) {
    int t = threadIdx.x;
    s  = red[0][t] + red[0][t + 64] + red[0][t + 128] + red[0][t + 192];
    s2 = red[1][t] + red[1][t + 64] + red[1][t + 128] + red[1][t + 192];
    pstat[((size_t)rg * 1024 + col) * 2]     = s;
    pstat[((size_t)rg * 1024 + col) * 2 + 1] = s2;
  }
}

// ---- finalize col BN: fold 32 rowgroup partials -> scl/bia ----
__global__ void k_stats_fin(const float* __restrict__ pstat,
                            const float* __restrict__ g, const float* __restrict__ be,
                            float* __restrict__ scl, float* __restrict__ bia) {
  int col = blockIdx.x * 256 + threadIdx.x;
  float s = 0.f, s2 = 0.f;
#pragma unroll
  for (int p = 0; p < 32; ++p) {
    s  += pstat[((size_t)p * 1024 + col) * 2];
    s2 += pstat[((size_t)p * 1024 + col) * 2 + 1];
  }
  float invN = 1.0f / (float)NB;
  float m = s * invN;
  float var = s2 * invN - m * m;
  float inv = rsqrtf(var + 1e-5f);
  scl[col] = g[col] * inv;
  bia[col] = be[col] - g[col] * inv * m;
}

// ---------------- a1 = bf16(relu(r0*scl + bia)) ----------------
__global__ void k_applyA1(const float* __restrict__ c0,
                          const float* __restrict__ scl, const float* __restrict__ bia,
                          u16* __restrict__ a1) {
  size_t i4 = ((size_t)blockIdx.x * 256 + threadIdx.x) * 4;
  int n = (int)(i4 & 1023);
  float4 v0 = *(const float4*)(c0 + i4);
  ushort4 o;
  o.x = f2bf(fmaxf(fmaf(v0.x, scl[n + 0], bia[n + 0]), 0.f));
  o.y = f2bf(fmaxf(fmaf(v0.y, scl[n + 1], bia[n + 1]), 0.f));
  o.z = f2bf(fmaxf(fmaf(v0.z, scl[n + 2], bia[n + 2]), 0.f));
  o.w = f2bf(fmaxf(fmaf(v0.w, scl[n + 3], bia[n + 3]), 0.f));
  *(ushort4*)(a1 + i4) = o;
}

// -------- y[b] = out_b + sum_n relu(h*scl+bia)*out_w[n] --------
__global__ void k_final(const float* __restrict__ h, const float* __restrict__ scl,
                        const float* __restrict__ bia, const float* __restrict__ ow,
                        const float* __restrict__ ob, float* __restrict__ y) {
  int lane = threadIdx.x & 63, wid = threadIdx.x >> 6;
  int row = blockIdx.x * 4 + wid;
  const float* hr = h + (size_t)row * 1024;
  float part = 0.f;
#pragma unroll
  for (int j = 0; j < 16; ++j) {
    int n = j * 64 + lane;
    float v = fmaxf(fmaf(hr[n], scl[n], bia[n]), 0.f);
    part = fmaf(v, ow[n], part);
  }
#pragma unroll
  for (int off = 32; off >= 1; off >>= 1) part += __shfl_xor(part, off);
  if (lane == 0) y[row] = part + ob[0];
}

extern "C" void kernel_launch(void* const* d_in, const int* in_sizes, int n_in,
                              void* d_out, int out_size, void* d_ws, size_t ws_size,
                              hipStream_t stream) {
  const int*   ids   = (const int*)d_in[0];
  const float* vals  = (const float*)d_in[1];
  const float* etab  = (const float*)d_in[2];
  const float* wb    = (const float*)d_in[3];
  const float* query = (const float*)d_in[4];
  const float* att   = (const float*)d_in[5];
  const float* bng   = (const float*)d_in[6];
  const float* w0    = (const float*)d_in[8];
  const float* g0    = (const float*)d_in[10];
  const float* be0   = (const float*)d_in[11];
  const float* w1    = (const float*)d_in[12];
  const float* g1    = (const float*)d_in[14];
  const float* be1   = (const float*)d_in[15];
  const float* outw  = (const float*)d_in[16];
  const float* outb  = (const float*)d_in[17];
  float* y = (float*)d_out;

  // workspace layout (peak ~195.6 MB):
  //   [0, 32K)            mt
  //   [32K, 33.59M)       w0bf (32MB, pre-scaled by arm-BN scl)
  //   [33.59M, 35.68M)    w1bf (2MB)
  //   [35.68M, 102.79M)   tbuf (64MB bf16)  -- alive through gemm0 (A operand)
  //   [102.79M, 166.90M)  c01 (8x8MB f32)   -- gemm0 partials; dead after red_stats<8>
  //   [102.79M, 136.33M)  h1 (4x8MB f32)    -- overlays dead c01; gemm1 partials
  //   [169.90M, 178.29M)  r0 (8MB f32)
  //   [178.29M, 182.48M)  a1 (4MB bf16)
  //   [186.68M, 195.07M)  h (8MB f32, summed)
  //   [195.07M, ...)      pstat1/pstat2/pstatO + BN scalars
  char* ws = (char*)d_ws;
  u16*   mt     = (u16*)(ws + 0);
  u16*   w0bf   = (u16*)(ws + 32768ull);
  u16*   w1bf   = (u16*)(ws + 33587200ull);
  u16*   tbuf   = (u16*)(ws + 35684352ull);
  float* c01    = (float*)(ws + 102793216ull);
  float* h1     = (float*)(ws + 102793216ull);
  float* r0     = (float*)(ws + 169902080ull);
  u16*   a1     = (u16*)(ws + 178290688ull);
  float* h      = (float*)(ws + 186679296ull);
  float* pstat1 = (float*)(ws + 195067904ull);
  float* pstat2 = (float*)(ws + 195330048ull);
  float* pstatO = (float*)(ws + 195592192ull);
  float* sclA   = (float*)(ws + 195608576ull);
  float* scl1   = (float*)(ws + 195609600ull);
  float* bia1   = (float*)(ws + 195613696ull);
  float* scl2   = (float*)(ws + 195617792ull);
  float* bia2   = (float*)(ws + 195621888ull);

  k_prep_M<<<64, 256, 0, stream>>>(wb, query, mt);
  k_cvt<<<1024, 256, 0, stream>>>(w1, w1bf, 1024 * 1024);
  k_mega<<<2048, 256, 0, stream>>>(ids, vals, etab, mt, att, tbuf);
  k_stats_o_part<<<dim3(256, 8), 256, 0, stream>>>(tbuf, pstatO);
  k_stats_o_fin<<<1, 256, 0, stream>>>(pstatO, bng, sclA);
  k_cvt_w0s<<<16384, 256, 0, stream>>>(w0, sclA, w0bf);
  // gemm0: A = tbuf directly (arm-BN scale folded into w0bf; bias terms cancel
  // in the following batch-BN). split-K=8 -> 1024 blocks = 4/CU.
  k_gemm<<<dim3(16, 8, 8), 256, 0, stream>>>(tbuf, w0bf, c01, 2048, 1024, 16384, 2048);
  k_red_stats<8><<<dim3(16, 32), 256, 0, stream>>>(c01, r0, pstat1);
  k_stats_fin<<<4, 256, 0, stream>>>(pstat1, g0, be0, scl1, bia1);
  k_applyA1<<<2048, 256, 0, stream>>>(r0, scl1, bia1, a1);
  // gemm1: split-K=4 -> 512 blocks = 2/CU; partials overlay dead c01.
  k_gemm<<<dim3(16, 8, 4), 256, 0, stream>>>(a1, w1bf, h1, 2048, 1024, 1024, 256);
  k_red_stats<4><<<dim3(16, 32), 256, 0, stream>>>(h1, h, pstat2);
  k_stats_fin<<<4, 256, 0, stream>>>(pstat2, g1, be1, scl2, bia2);
  k_final<<<512, 256, 0, stream>>>(h, scl2, bia2, outw, outb, y);
}

// Round 6
// 290.092 us; speedup vs baseline: 3.5268x; 1.0695x over previous
//
#include <hip/hip_runtime.h>

typedef unsigned short u16;
typedef __attribute__((ext_vector_type(8))) short bf16x8;
typedef __attribute__((ext_vector_type(8))) unsigned short u16x8;
typedef __attribute__((ext_vector_type(4))) float f32x4;

__device__ __forceinline__ u16 f2bf(float f) {
  unsigned u = __builtin_bit_cast(unsigned, f);
  u += 0x7fffu + ((u >> 16) & 1u);
  return (u16)(u >> 16);
}
__device__ __forceinline__ float bf2f(u16 h) {
  unsigned u = ((unsigned)h) << 16;
  return __builtin_bit_cast(float, u);
}

#define NB 2048
#define NF 100
#define NE 64
#define NO 256
#define OCH 64
#define EMB_ST 72
#define EMBT_ST 136
#define GAW_ST 136

#define GLOAD16(gsrc, ldst)                                                        \
  __builtin_amdgcn_global_load_lds(                                                \
      (const __attribute__((address_space(1))) unsigned int*)(gsrc),               \
      (__attribute__((address_space(3))) unsigned int*)(ldst), 16, 0, 0)

// ---------------- prep: M[o][e] = 0.0625 * sum_k query[o,k]*Wb[k,e] ----------------
__global__ void k_prep_M(const float* __restrict__ wb, const float* __restrict__ q,
                         u16* __restrict__ mt) {
  int idx = blockIdx.x * 256 + threadIdx.x;   // 16384 = 256*64
  int o = idx >> 6, e = idx & 63;
  float s = 0.f;
  for (int k = 0; k < 64; ++k) s = fmaf(q[o * 64 + k], wb[k * 64 + e], s);
  mt[idx] = f2bf(s * 0.0625f);   // folds DK^-0.5 (0.125) and (alpha-1) (0.5)
}

// ---------------- f32 -> bf16 conversion ----------------
__global__ void k_cvt(const float* __restrict__ in, u16* __restrict__ out, int n) {
  int i4 = (blockIdx.x * 256 + threadIdx.x) * 4;
  if (i4 >= n) return;
  float4 v = *(const float4*)(in + i4);
  ushort4 o;
  o.x = f2bf(v.x); o.y = f2bf(v.y); o.z = f2bf(v.z); o.w = f2bf(v.w);
  *(ushort4*)(out + i4) = o;
}

// ------- f32 -> bf16 with per-k scale: w0'[n][k] = bf16(w0[n][k] * scl[k>>6]) -------
__global__ void k_cvt_w0s(const float* __restrict__ in, const float* __restrict__ scl,
                          u16* __restrict__ out) {
  size_t i4 = ((size_t)blockIdx.x * 256 + threadIdx.x) * 4;
  int o = (int)((i4 >> 6) & 255);
  float sc = scl[o];
  float4 v = *(const float4*)(in + i4);
  ushort4 u;
  u.x = f2bf(v.x * sc); u.y = f2bf(v.y * sc);
  u.z = f2bf(v.z * sc); u.w = f2bf(v.w * sc);
  *(ushort4*)(out + i4) = u;
}

// ------- fused gather + (per-o-chunk: gates GEMM + entmax + arm GEMM + exp-1) -------
// Quad-lane q of row r owns f positions {j*16 + q*4 + t : j<7, t<4} (112 slots,
// 100 real + 12 masked) -> all gate/aw LDS traffic is aligned ushort4, att loads
// are aligned float4. Entmax: pure Newton x6 (monotone from tau0 = mx-1 on the
// convex decreasing f; worst case (uniform 100) converges to 5e-7 in 6 iters).
__global__ __launch_bounds__(256) void k_mega(
    const int* __restrict__ ids, const float* __restrict__ vals,
    const float* __restrict__ etab, const u16* __restrict__ mt,
    const float* __restrict__ att, u16* __restrict__ tbuf) {
  __shared__ u16 s_emb[112][EMB_ST];     // [f][e], rows 100..111 zero; stride 72 = aligned b128
  __shared__ u16 s_embT[64][EMBT_ST];    // [e][f], cols 100..135 zero
  __shared__ u16 s_gaw[64][GAW_ST];      // phase1-2: gates; phase2-3: p*att (quad-local alias)
  __shared__ float s_rs[64];             // per-row 1/sum(p), folded into phase-3 acc

  const int tid = threadIdx.x;
  const int lane = tid & 63;
  const int wid = tid >> 6;
  const int b = blockIdx.x;

  // phase 0: gather emb = emb_table[ids]*clip(v)  (once per b)
  for (int f = wid; f < NF; f += 4) {
    int id = ids[b * NF + f];
    float v = vals[b * NF + f];
    v = fminf(fmaxf(v, 0.001f), 1.0f);
    float ev = etab[(size_t)id * NE + lane] * v;
    u16 bf = f2bf(ev);
    s_emb[f][lane] = bf;
    s_embT[lane][f] = bf;
  }
  for (int i = tid; i < 12 * EMB_ST; i += 256) s_emb[100 + i / EMB_ST][i % EMB_ST] = 0;
  for (int i = tid; i < 64 * 36; i += 256) s_embT[i / 36][100 + i % 36] = 0;
  // s_gaw cols 112..135: zeroed once; never written afterwards (phase 1 writes
  // fc<100, phase 2 writes f<112).
  for (int i = tid; i < 64 * 24; i += 256) s_gaw[i / 24][112 + i % 24] = 0;
  __syncthreads();

  for (int oc = 0; oc < 4; ++oc) {
    const int obase = oc * OCH;
    bf16x8 amt[2];
#pragma unroll
    for (int kh = 0; kh < 2; ++kh)
      amt[kh] = *(const bf16x8*)(mt + ((obase + wid * 16 + (lane & 15)) * 64 +
                                       kh * 32 + ((lane >> 4) * 8)));

    // phase 1: gates[o][f] = M[o,:]·emb[f,:]
#pragma unroll
    for (int ft = 0; ft < 7; ++ft) {
      f32x4 acc = {0.f, 0.f, 0.f, 0.f};
#pragma unroll
      for (int kh = 0; kh < 2; ++kh) {
        bf16x8 bfr = *(const bf16x8*)&s_emb[ft * 16 + (lane & 15)][kh * 32 + ((lane >> 4) * 8)];
        acc = __builtin_amdgcn_mfma_f32_16x16x32_bf16(amt[kh], bfr, acc, 0, 0, 0);
      }
      int fc = ft * 16 + (lane & 15);
      if (fc < NF) {
#pragma unroll
        for (int i = 0; i < 4; ++i)
          s_gaw[wid * 16 + ((lane >> 4) * 4) + i][fc] = f2bf(acc[i]);
      }
    }
    __syncthreads();

    // phase 2: entmax(alpha=1.5), pure Newton x6, quad (4 lanes) per o-row
    {
      const int q = tid & 3;
      const int r = tid >> 2;
      const int og = obase + r;
      float x[28];
#pragma unroll
      for (int j = 0; j < 7; ++j) {
        ushort4 g = *(const ushort4*)&s_gaw[r][j * 16 + q * 4];
        x[j * 4 + 0] = bf2f(g.x); x[j * 4 + 1] = bf2f(g.y);
        x[j * 4 + 2] = bf2f(g.z); x[j * 4 + 3] = bf2f(g.w);
      }
      if (q > 0) { x[24] = -1e30f; x[25] = -1e30f; x[26] = -1e30f; x[27] = -1e30f; }
      float attv[28];
#pragma unroll
      for (int j = 0; j < 7; ++j) {
        if (j < 6 || q == 0) {
          float4 av = *(const float4*)(att + og * NF + j * 16 + q * 4);
          attv[j * 4 + 0] = av.x; attv[j * 4 + 1] = av.y;
          attv[j * 4 + 2] = av.z; attv[j * 4 + 3] = av.w;
        } else {
          attv[j * 4 + 0] = 0.f; attv[j * 4 + 1] = 0.f;
          attv[j * 4 + 2] = 0.f; attv[j * 4 + 3] = 0.f;
        }
      }
      float m0 = x[0], m1 = x[1];
#pragma unroll
      for (int j = 2; j < 28; j += 2) { m0 = fmaxf(m0, x[j]); m1 = fmaxf(m1, x[j + 1]); }
      float mx = fmaxf(m0, m1);
      mx = fmaxf(mx, __shfl_xor(mx, 1));
      mx = fmaxf(mx, __shfl_xor(mx, 2));
      float tau = mx - 1.0f;
#pragma unroll
      for (int it = 0; it < 6; ++it) {
        float s0 = 0.f, s1 = 0.f, t0 = 0.f, t1 = 0.f;
#pragma unroll
        for (int j = 0; j < 14; ++j) {
          float d0 = fmaxf(x[j] - tau, 0.f);
          float d1 = fmaxf(x[j + 14] - tau, 0.f);
          s0 = fmaf(d0, d0, s0); s1 = fmaf(d1, d1, s1);
          t0 += d0; t1 += d1;
        }
        float s = s0 + s1, sd = t0 + t1;
        s += __shfl_xor(s, 1);
        s += __shfl_xor(s, 2);
        sd += __shfl_xor(sd, 1);
        sd += __shfl_xor(sd, 2);
        tau += (s - 1.0f) / (2.0f * sd + 1e-30f);
      }
      float s0 = 0.f, s1 = 0.f;
#pragma unroll
      for (int j = 0; j < 14; ++j) {
        float d0 = fmaxf(x[j] - tau, 0.f);
        float d1 = fmaxf(x[j + 14] - tau, 0.f);
        x[j] = d0 * d0;
        x[j + 14] = d1 * d1;
        s0 += x[j]; s1 += x[j + 14];
      }
      float s = s0 + s1;
      s += __shfl_xor(s, 1);
      s += __shfl_xor(s, 2);
      if (q == 0) s_rs[r] = 1.0f / s;
      // aw = p*att (1/sum folded into phase 3 via s_rs); quad-local alias, no barrier
#pragma unroll
      for (int j = 0; j < 7; ++j) {
        ushort4 w;
        w.x = f2bf(x[j * 4 + 0] * attv[j * 4 + 0]);
        w.y = f2bf(x[j * 4 + 1] * attv[j * 4 + 1]);
        w.z = f2bf(x[j * 4 + 2] * attv[j * 4 + 2]);
        w.w = f2bf(x[j * 4 + 3] * attv[j * 4 + 3]);
        *(ushort4*)&s_gaw[r][j * 16 + q * 4] = w;
      }
    }
    __syncthreads();

    // phase 3: arm[o][e] = rs[o] * sum_f aw[o][f]*emb[f][e];  store t = exp(arm)-1
    f32x4 acc[4] = {};
#pragma unroll
    for (int h = 0; h < 4; ++h) {
      bf16x8 afr = *(const bf16x8*)&s_gaw[wid * 16 + (lane & 15)][h * 32 + ((lane >> 4) * 8)];
#pragma unroll
      for (int et = 0; et < 4; ++et) {
        bf16x8 bfr = *(const bf16x8*)&s_embT[et * 16 + (lane & 15)][h * 32 + ((lane >> 4) * 8)];
        acc[et] = __builtin_amdgcn_mfma_f32_16x16x32_bf16(afr, bfr, acc[et], 0, 0, 0);
      }
    }
    const int rbase = wid * 16 + ((lane >> 4) * 4);
    float rs4[4];
#pragma unroll
    for (int i = 0; i < 4; ++i) rs4[i] = s_rs[rbase + i];
    size_t orow = (size_t)b * NO + obase + rbase;
#pragma unroll
    for (int et = 0; et < 4; ++et) {
      int e = et * 16 + (lane & 15);
#pragma unroll
      for (int i = 0; i < 4; ++i)
        tbuf[(orow + i) * 64 + e] = f2bf(__expf(acc[et][i] * rs4[i]) - 1.0f);
    }
    __syncthreads();   // protect s_gaw/s_rs for next oc
  }
}

// ------- per-o BN stats stage A: partial (s,s2) over a 256-batch slice -------
__global__ void k_stats_o_part(const u16* __restrict__ t, float* __restrict__ pstat) {
  const int o = blockIdx.x, bs = blockIdx.y;
  const int e = threadIdx.x & 63, bt = threadIdx.x >> 6;
  float s = 0.f, s2 = 0.f;
  for (int b = bs * 256 + bt; b < bs * 256 + 256; b += 4) {
    float v = bf2f(t[((size_t)b * NO + o) * 64 + e]);
    s += v;
    s2 = fmaf(v, v, s2);
  }
  __shared__ float red[2][256];
  red[0][threadIdx.x] = s; red[1][threadIdx.x] = s2;
  __syncthreads();
  for (int st = 128; st >= 1; st >>= 1) {
    if (threadIdx.x < st) {
      red[0][threadIdx.x] += red[0][threadIdx.x + st];
      red[1][threadIdx.x] += red[1][threadIdx.x + st];
    }
    __syncthreads();
  }
  if (threadIdx.x == 0) {
    pstat[((size_t)bs * NO + o) * 2] = red[0][0];
    pstat[((size_t)bs * NO + o) * 2 + 1] = red[1][0];
  }
}

// ------- per-o BN stats stage B: scl = g*rsqrt(var+eps) -------
__global__ void k_stats_o_fin(const float* __restrict__ pstat, const float* __restrict__ g,
                              float* __restrict__ scl) {
  int o = threadIdx.x;
  float s = 0.f, s2 = 0.f;
#pragma unroll
  for (int p = 0; p < 8; ++p) {
    s  += pstat[((size_t)p * NO + o) * 2];
    s2 += pstat[((size_t)p * NO + o) * 2 + 1];
  }
  float invN = 1.0f / (float)(NB * 64);
  float m = s * invN;
  float var = s2 * invN - m * m;
  scl[o] = g[o] * rsqrtf(var + 1e-5f);
}

// ---- bf16 GEMM, C[m][n] = sum_k A[m][k]*B[n][k] (B^T layout), split-K ----
__global__ __launch_bounds__(256) void k_gemm(const u16* __restrict__ A,
                                              const u16* __restrict__ B,
                                              float* __restrict__ C,
                                              int M, int N, int K, int ksz) {
  __shared__ u16 sA[128][64];
  __shared__ u16 sB[128][64];
  const int tid = threadIdx.x, lane = tid & 63, wid = tid >> 6;
  const int wr = wid >> 1, wc = wid & 1;
  const int m0 = blockIdx.x * 128, n0 = blockIdx.y * 128;
  const int k0 = blockIdx.z * ksz;
  C += (size_t)blockIdx.z * ((size_t)M * N);
  f32x4 acc[4][4];
#pragma unroll
  for (int mi = 0; mi < 4; ++mi)
#pragma unroll
    for (int ni = 0; ni < 4; ++ni) acc[mi][ni] = (f32x4){0.f, 0.f, 0.f, 0.f};

  const int lrow = lane >> 3;    // 0..7
  const int lch = lane & 7;      // 16B chunk in row
  const u16* gA = A + (size_t)(m0 + wid * 32 + lrow) * K + k0 + lch * 8;
  const u16* gB = B + (size_t)(n0 + wid * 32 + lrow) * K + k0 + lch * 8;
  u16* lA = &sA[wid * 32][0];    // wave-uniform LDS base
  u16* lB = &sB[wid * 32][0];

  const int nkt = ksz / 64;
  for (int kt = 0; kt < nkt; ++kt) {
#pragma unroll
    for (int i = 0; i < 4; ++i) {
      GLOAD16(gA + (size_t)i * 8 * K, lA + i * 512);
      GLOAD16(gB + (size_t)i * 8 * K, lB + i * 512);
    }
    gA += 64; gB += 64;
    __syncthreads();
#pragma unroll
    for (int kh = 0; kh < 2; ++kh) {
      bf16x8 af[4], bfv[4];
#pragma unroll
      for (int i = 0; i < 4; ++i) {
        af[i]  = *(const bf16x8*)&sA[wr * 64 + i * 16 + (lane & 15)][kh * 32 + ((lane >> 4) * 8)];
        bfv[i] = *(const bf16x8*)&sB[wc * 64 + i * 16 + (lane & 15)][kh * 32 + ((lane >> 4) * 8)];
      }
#pragma unroll
      for (int mi = 0; mi < 4; ++mi)
#pragma unroll
        for (int ni = 0; ni < 4; ++ni)
          acc[mi][ni] = __builtin_amdgcn_mfma_f32_16x16x32_bf16(af[mi], bfv[ni], acc[mi][ni], 0, 0, 0);
    }
    __syncthreads();
  }
#pragma unroll
  for (int mi = 0; mi < 4; ++mi) {
    int m = m0 + wr * 64 + mi * 16 + ((lane >> 4) * 4);
#pragma unroll
    for (int ni = 0; ni < 4; ++ni) {
      int n = n0 + wc * 64 + ni * 16 + (lane & 15);
#pragma unroll
      for (int i = 0; i < 4; ++i) C[(size_t)(m + i) * N + n] = acc[mi][ni][i];
    }
  }
}

// ---- fused: r = sum of NP split-K partials  +  per-(rowgroup,col) BN partial stats ----
template <int NP>
__global__ void k_red_stats(const float* __restrict__ c, float* __restrict__ r,
                            float* __restrict__ pstat) {
  const int col = blockIdx.x * 64 + (threadIdx.x & 63);
  const int rt = threadIdx.x >> 6;
  const int rg = blockIdx.y;
  const size_t ps = (size_t)NB * 1024;
  float s = 0.f, s2 = 0.f;
  for (int rr = rt; rr < 64; rr += 4) {
    size_t idx = (size_t)(rg * 64 + rr) * 1024 + col;
    float v = c[idx];
#pragma unroll
    for (int p = 1; p < NP; ++p) v += c[p * ps + idx];
    r[idx] = v;
    s += v;
    s2 = fmaf(v, v, s2);
  }
  __shared__ float red[2][256];
  red[0][threadIdx.x] = s; red[1][threadIdx.x] = s2;
  __syncthreads();
  if (threadIdx.x < 64) {
    int t = threadIdx.x;
    s  = red[0][t] + red[0][t + 64] + red[0][t + 128] + red[0][t + 192];
    s2 = red[1][t] + red[1][t + 64] + red[1][t + 128] + red[1][t + 192];
    pstat[((size_t)rg * 1024 + col) * 2]     = s;
    pstat[((size_t)rg * 1024 + col) * 2 + 1] = s2;
  }
}

// ---- finalize col BN: fold 32 rowgroup partials -> scl/bia ----
__global__ void k_stats_fin(const float* __restrict__ pstat,
                            const float* __restrict__ g, const float* __restrict__ be,
                            float* __restrict__ scl, float* __restrict__ bia) {
  int col = blockIdx.x * 256 + threadIdx.x;
  float s = 0.f, s2 = 0.f;
#pragma unroll
  for (int p = 0; p < 32; ++p) {
    s  += pstat[((size_t)p * 1024 + col) * 2];
    s2 += pstat[((size_t)p * 1024 + col) * 2 + 1];
  }
  float invN = 1.0f / (float)NB;
  float m = s * invN;
  float var = s2 * invN - m * m;
  float inv = rsqrtf(var + 1e-5f);
  scl[col] = g[col] * inv;
  bia[col] = be[col] - g[col] * inv * m;
}

// ---------------- a1 = bf16(relu(r0*scl + bia)) ----------------
__global__ void k_applyA1(const float* __restrict__ c0,
                          const float* __restrict__ scl, const float* __restrict__ bia,
                          u16* __restrict__ a1) {
  size_t i4 = ((size_t)blockIdx.x * 256 + threadIdx.x) * 4;
  int n = (int)(i4 & 1023);
  float4 v0 = *(const float4*)(c0 + i4);
  ushort4 o;
  o.x = f2bf(fmaxf(fmaf(v0.x, scl[n + 0], bia[n + 0]), 0.f));
  o.y = f2bf(fmaxf(fmaf(v0.y, scl[n + 1], bia[n + 1]), 0.f));
  o.z = f2bf(fmaxf(fmaf(v0.z, scl[n + 2], bia[n + 2]), 0.f));
  o.w = f2bf(fmaxf(fmaf(v0.w, scl[n + 3], bia[n + 3]), 0.f));
  *(ushort4*)(a1 + i4) = o;
}

// -------- y[b] = out_b + sum_n relu(h*scl+bia)*out_w[n] --------
__global__ void k_final(const float* __restrict__ h, const float* __restrict__ scl,
                        const float* __restrict__ bia, const float* __restrict__ ow,
                        const float* __restrict__ ob, float* __restrict__ y) {
  int lane = threadIdx.x & 63, wid = threadIdx.x >> 6;
  int row = blockIdx.x * 4 + wid;
  const float* hr = h + (size_t)row * 1024;
  float part = 0.f;
#pragma unroll
  for (int j = 0; j < 16; ++j) {
    int n = j * 64 + lane;
    float v = fmaxf(fmaf(hr[n], scl[n], bia[n]), 0.f);
    part = fmaf(v, ow[n], part);
  }
#pragma unroll
  for (int off = 32; off >= 1; off >>= 1) part += __shfl_xor(part, off);
  if (lane == 0) y[row] = part + ob[0];
}

extern "C" void kernel_launch(void* const* d_in, const int* in_sizes, int n_in,
                              void* d_out, int out_size, void* d_ws, size_t ws_size,
                              hipStream_t stream) {
  const int*   ids   = (const int*)d_in[0];
  const float* vals  = (const float*)d_in[1];
  const float* etab  = (const float*)d_in[2];
  const float* wb    = (const float*)d_in[3];
  const float* query = (const float*)d_in[4];
  const float* att   = (const float*)d_in[5];
  const float* bng   = (const float*)d_in[6];
  const float* w0    = (const float*)d_in[8];
  const float* g0    = (const float*)d_in[10];
  const float* be0   = (const float*)d_in[11];
  const float* w1    = (const float*)d_in[12];
  const float* g1    = (const float*)d_in[14];
  const float* be1   = (const float*)d_in[15];
  const float* outw  = (const float*)d_in[16];
  const float* outb  = (const float*)d_in[17];
  float* y = (float*)d_out;

  // workspace layout (peak ~195.6 MB):
  //   [0, 32K)            mt
  //   [32K, 33.59M)       w0bf (32MB, pre-scaled by arm-BN scl)
  //   [33.59M, 35.68M)    w1bf (2MB)
  //   [35.68M, 102.79M)   tbuf (64MB bf16)  -- alive through gemm0 (A operand)
  //   [102.79M, 166.90M)  c01 (8x8MB f32)   -- gemm0 partials; dead after red_stats<8>
  //   [102.79M, 136.33M)  h1 (4x8MB f32)    -- overlays dead c01; gemm1 partials
  //   [169.90M, 178.29M)  r0 (8MB f32)
  //   [178.29M, 182.48M)  a1 (4MB bf16)
  //   [186.68M, 195.07M)  h (8MB f32, summed)
  //   [195.07M, ...)      pstat1/pstat2/pstatO + BN scalars
  char* ws = (char*)d_ws;
  u16*   mt     = (u16*)(ws + 0);
  u16*   w0bf   = (u16*)(ws + 32768ull);
  u16*   w1bf   = (u16*)(ws + 33587200ull);
  u16*   tbuf   = (u16*)(ws + 35684352ull);
  float* c01    = (float*)(ws + 102793216ull);
  float* h1     = (float*)(ws + 102793216ull);
  float* r0     = (float*)(ws + 169902080ull);
  u16*   a1     = (u16*)(ws + 178290688ull);
  float* h      = (float*)(ws + 186679296ull);
  float* pstat1 = (float*)(ws + 195067904ull);
  float* pstat2 = (float*)(ws + 195330048ull);
  float* pstatO = (float*)(ws + 195592192ull);
  float* sclA   = (float*)(ws + 195608576ull);
  float* scl1   = (float*)(ws + 195609600ull);
  float* bia1   = (float*)(ws + 195613696ull);
  float* scl2   = (float*)(ws + 195617792ull);
  float* bia2   = (float*)(ws + 195621888ull);

  k_prep_M<<<64, 256, 0, stream>>>(wb, query, mt);
  k_cvt<<<1024, 256, 0, stream>>>(w1, w1bf, 1024 * 1024);
  k_mega<<<2048, 256, 0, stream>>>(ids, vals, etab, mt, att, tbuf);
  k_stats_o_part<<<dim3(256, 8), 256, 0, stream>>>(tbuf, pstatO);
  k_stats_o_fin<<<1, 256, 0, stream>>>(pstatO, bng, sclA);
  k_cvt_w0s<<<16384, 256, 0, stream>>>(w0, sclA, w0bf);
  // gemm0: A = tbuf directly (arm-BN scale folded into w0bf; bias terms cancel
  // in the following batch-BN). split-K=8 -> 1024 blocks = 4/CU.
  k_gemm<<<dim3(16, 8, 8), 256, 0, stream>>>(tbuf, w0bf, c01, 2048, 1024, 16384, 2048);
  k_red_stats<8><<<dim3(16, 32), 256, 0, stream>>>(c01, r0, pstat1);
  k_stats_fin<<<4, 256, 0, stream>>>(pstat1, g0, be0, scl1, bia1);
  k_applyA1<<<2048, 256, 0, stream>>>(r0, scl1, bia1, a1);
  // gemm1: split-K=4 -> 512 blocks = 2/CU; partials overlay dead c01.
  k_gemm<<<dim3(16, 8, 4), 256, 0, stream>>>(a1, w1bf, h1, 2048, 1024, 1024, 256);
  k_red_stats<4><<<dim3(16, 32), 256, 0, stream>>>(h1, h, pstat2);
  k_stats_fin<<<4, 256, 0, stream>>>(pstat2, g1, be1, scl2, bia2);
  k_final<<<512, 256, 0, stream>>>(h, scl2, bia2, outw, outb, y);
}

// Round 7
// 273.887 us; speedup vs baseline: 3.7354x; 1.0592x over previous
//
#include <hip/hip_runtime.h>

typedef unsigned short u16;
typedef __attribute__((ext_vector_type(8))) short bf16x8;
typedef __attribute__((ext_vector_type(8))) unsigned short u16x8;
typedef __attribute__((ext_vector_type(4))) float f32x4;

__device__ __forceinline__ u16 f2bf(float f) {
  unsigned u = __builtin_bit_cast(unsigned, f);
  u += 0x7fffu + ((u >> 16) & 1u);
  return (u16)(u >> 16);
}
__device__ __forceinline__ float bf2f(u16 h) {
  unsigned u = ((unsigned)h) << 16;
  return __builtin_bit_cast(float, u);
}

#define NB 2048
#define NF 100
#define NE 64
#define NO 256
#define OCH 64
#define EMB_ST 72
#define EMBT_ST 136
#define GAW_ST 136

#define GLOAD16(gsrc, ldst)                                                        \
  __builtin_amdgcn_global_load_lds(                                                \
      (const __attribute__((address_space(1))) unsigned int*)(gsrc),               \
      (__attribute__((address_space(3))) unsigned int*)(ldst), 16, 0, 0)

// ---------------- prep: M[o][e] = 0.0625 * sum_k query[o,k]*Wb[k,e] ----------------
__global__ void k_prep_M(const float* __restrict__ wb, const float* __restrict__ q,
                         u16* __restrict__ mt) {
  int idx = blockIdx.x * 256 + threadIdx.x;   // 16384 = 256*64
  int o = idx >> 6, e = idx & 63;
  float s = 0.f;
  for (int k = 0; k < 64; ++k) s = fmaf(q[o * 64 + k], wb[k * 64 + e], s);
  mt[idx] = f2bf(s * 0.0625f);   // folds DK^-0.5 (0.125) and (alpha-1) (0.5)
}

// ---------------- f32 -> bf16 conversion ----------------
__global__ void k_cvt(const float* __restrict__ in, u16* __restrict__ out, int n) {
  int i4 = (blockIdx.x * 256 + threadIdx.x) * 4;
  if (i4 >= n) return;
  float4 v = *(const float4*)(in + i4);
  ushort4 o;
  o.x = f2bf(v.x); o.y = f2bf(v.y); o.z = f2bf(v.z); o.w = f2bf(v.w);
  *(ushort4*)(out + i4) = o;
}

// ------- f32 -> bf16 with per-k scale: w0'[n][k] = bf16(w0[n][k] * scl[k>>6]) -------
__global__ void k_cvt_w0s(const float* __restrict__ in, const float* __restrict__ scl,
                          u16* __restrict__ out) {
  size_t i4 = ((size_t)blockIdx.x * 256 + threadIdx.x) * 4;
  int o = (int)((i4 >> 6) & 255);
  float sc = scl[o];
  float4 v = *(const float4*)(in + i4);
  ushort4 u;
  u.x = f2bf(v.x * sc); u.y = f2bf(v.y * sc);
  u.z = f2bf(v.z * sc); u.w = f2bf(v.w * sc);
  *(ushort4*)(out + i4) = u;
}

// ------- fused gather + (per-o-chunk: gates GEMM + entmax + arm GEMM + exp-1) -------
__global__ __launch_bounds__(256) void k_mega(
    const int* __restrict__ ids, const float* __restrict__ vals,
    const float* __restrict__ etab, const u16* __restrict__ mt,
    const float* __restrict__ att, u16* __restrict__ tbuf) {
  __shared__ u16 s_emb[112][EMB_ST];     // [f][e], rows 100..111 zero; stride 72 = aligned b128
  __shared__ u16 s_embT[64][EMBT_ST];    // [e][f], cols 100..135 zero
  __shared__ u16 s_gaw[64][GAW_ST];      // phase1-2: gates; phase2-3: p*att (quad-local alias)
  __shared__ float s_rs[64];             // per-row 1/sum(p), folded into phase-3 acc

  const int tid = threadIdx.x;
  const int lane = tid & 63;
  const int wid = tid >> 6;
  const int b = blockIdx.x;

  // phase 0: gather emb = emb_table[ids]*clip(v)  (once per b)
  for (int f = wid; f < NF; f += 4) {
    int id = ids[b * NF + f];
    float v = vals[b * NF + f];
    v = fminf(fmaxf(v, 0.001f), 1.0f);
    float ev = etab[(size_t)id * NE + lane] * v;
    u16 bf = f2bf(ev);
    s_emb[f][lane] = bf;
    s_embT[lane][f] = bf;
  }
  for (int i = tid; i < 12 * EMB_ST; i += 256) s_emb[100 + i / EMB_ST][i % EMB_ST] = 0;
  for (int i = tid; i < 64 * 36; i += 256) s_embT[i / 36][100 + i % 36] = 0;
  for (int i = tid; i < 64 * 24; i += 256) s_gaw[i / 24][112 + i % 24] = 0;
  __syncthreads();

  for (int oc = 0; oc < 4; ++oc) {
    const int obase = oc * OCH;
    bf16x8 amt[2];
#pragma unroll
    for (int kh = 0; kh < 2; ++kh)
      amt[kh] = *(const bf16x8*)(mt + ((obase + wid * 16 + (lane & 15)) * 64 +
                                       kh * 32 + ((lane >> 4) * 8)));

    // phase 1: gates[o][f] = M[o,:]·emb[f,:]
#pragma unroll
    for (int ft = 0; ft < 7; ++ft) {
      f32x4 acc = {0.f, 0.f, 0.f, 0.f};
#pragma unroll
      for (int kh = 0; kh < 2; ++kh) {
        bf16x8 bfr = *(const bf16x8*)&s_emb[ft * 16 + (lane & 15)][kh * 32 + ((lane >> 4) * 8)];
        acc = __builtin_amdgcn_mfma_f32_16x16x32_bf16(amt[kh], bfr, acc, 0, 0, 0);
      }
      int fc = ft * 16 + (lane & 15);
      if (fc < NF) {
#pragma unroll
        for (int i = 0; i < 4; ++i)
          s_gaw[wid * 16 + ((lane >> 4) * 4) + i][fc] = f2bf(acc[i]);
      }
    }
    __syncthreads();

    // phase 2: entmax(alpha=1.5), pure Newton x6, quad (4 lanes) per o-row
    {
      const int q = tid & 3;
      const int r = tid >> 2;
      const int og = obase + r;
      float x[28];
#pragma unroll
      for (int j = 0; j < 7; ++j) {
        ushort4 g = *(const ushort4*)&s_gaw[r][j * 16 + q * 4];
        x[j * 4 + 0] = bf2f(g.x); x[j * 4 + 1] = bf2f(g.y);
        x[j * 4 + 2] = bf2f(g.z); x[j * 4 + 3] = bf2f(g.w);
      }
      if (q > 0) { x[24] = -1e30f; x[25] = -1e30f; x[26] = -1e30f; x[27] = -1e30f; }
      float attv[28];
#pragma unroll
      for (int j = 0; j < 7; ++j) {
        if (j < 6 || q == 0) {
          float4 av = *(const float4*)(att + og * NF + j * 16 + q * 4);
          attv[j * 4 + 0] = av.x; attv[j * 4 + 1] = av.y;
          attv[j * 4 + 2] = av.z; attv[j * 4 + 3] = av.w;
        } else {
          attv[j * 4 + 0] = 0.f; attv[j * 4 + 1] = 0.f;
          attv[j * 4 + 2] = 0.f; attv[j * 4 + 3] = 0.f;
        }
      }
      float m0 = x[0], m1 = x[1];
#pragma unroll
      for (int j = 2; j < 28; j += 2) { m0 = fmaxf(m0, x[j]); m1 = fmaxf(m1, x[j + 1]); }
      float mx = fmaxf(m0, m1);
      mx = fmaxf(mx, __shfl_xor(mx, 1));
      mx = fmaxf(mx, __shfl_xor(mx, 2));
      float tau = mx - 1.0f;
#pragma unroll
      for (int it = 0; it < 6; ++it) {
        float s0 = 0.f, s1 = 0.f, t0 = 0.f, t1 = 0.f;
#pragma unroll
        for (int j = 0; j < 14; ++j) {
          float d0 = fmaxf(x[j] - tau, 0.f);
          float d1 = fmaxf(x[j + 14] - tau, 0.f);
          s0 = fmaf(d0, d0, s0); s1 = fmaf(d1, d1, s1);
          t0 += d0; t1 += d1;
        }
        float s = s0 + s1, sd = t0 + t1;
        s += __shfl_xor(s, 1);
        s += __shfl_xor(s, 2);
        sd += __shfl_xor(sd, 1);
        sd += __shfl_xor(sd, 2);
        tau += (s - 1.0f) / (2.0f * sd + 1e-30f);
      }
      float s0 = 0.f, s1 = 0.f;
#pragma unroll
      for (int j = 0; j < 14; ++j) {
        float d0 = fmaxf(x[j] - tau, 0.f);
        float d1 = fmaxf(x[j + 14] - tau, 0.f);
        x[j] = d0 * d0;
        x[j + 14] = d1 * d1;
        s0 += x[j]; s1 += x[j + 14];
      }
      float s = s0 + s1;
      s += __shfl_xor(s, 1);
      s += __shfl_xor(s, 2);
      if (q == 0) s_rs[r] = 1.0f / s;
#pragma unroll
      for (int j = 0; j < 7; ++j) {
        ushort4 w;
        w.x = f2bf(x[j * 4 + 0] * attv[j * 4 + 0]);
        w.y = f2bf(x[j * 4 + 1] * attv[j * 4 + 1]);
        w.z = f2bf(x[j * 4 + 2] * attv[j * 4 + 2]);
        w.w = f2bf(x[j * 4 + 3] * attv[j * 4 + 3]);
        *(ushort4*)&s_gaw[r][j * 16 + q * 4] = w;
      }
    }
    __syncthreads();

    // phase 3: arm[o][e] = rs[o] * sum_f aw[o][f]*emb[f][e];  store t = exp(arm)-1
    f32x4 acc[4] = {};
#pragma unroll
    for (int h = 0; h < 4; ++h) {
      bf16x8 afr = *(const bf16x8*)&s_gaw[wid * 16 + (lane & 15)][h * 32 + ((lane >> 4) * 8)];
#pragma unroll
      for (int et = 0; et < 4; ++et) {
        bf16x8 bfr = *(const bf16x8*)&s_embT[et * 16 + (lane & 15)][h * 32 + ((lane >> 4) * 8)];
        acc[et] = __builtin_amdgcn_mfma_f32_16x16x32_bf16(afr, bfr, acc[et], 0, 0, 0);
      }
    }
    const int rbase = wid * 16 + ((lane >> 4) * 4);
    float rs4[4];
#pragma unroll
    for (int i = 0; i < 4; ++i) rs4[i] = s_rs[rbase + i];
    size_t orow = (size_t)b * NO + obase + rbase;
#pragma unroll
    for (int et = 0; et < 4; ++et) {
      int e = et * 16 + (lane & 15);
#pragma unroll
      for (int i = 0; i < 4; ++i)
        tbuf[(orow + i) * 64 + e] = f2bf(__expf(acc[et][i] * rs4[i]) - 1.0f);
    }
    __syncthreads();   // protect s_gaw/s_rs for next oc
  }
}

// ------- per-o BN stats stage A: partial (s,s2) over a 256-batch slice -------
__global__ void k_stats_o_part(const u16* __restrict__ t, float* __restrict__ pstat) {
  const int o = blockIdx.x, bs = blockIdx.y;
  const int e = threadIdx.x & 63, bt = threadIdx.x >> 6;
  float s = 0.f, s2 = 0.f;
  for (int b = bs * 256 + bt; b < bs * 256 + 256; b += 4) {
    float v = bf2f(t[((size_t)b * NO + o) * 64 + e]);
    s += v;
    s2 = fmaf(v, v, s2);
  }
  __shared__ float red[2][256];
  red[0][threadIdx.x] = s; red[1][threadIdx.x] = s2;
  __syncthreads();
  for (int st = 128; st >= 1; st >>= 1) {
    if (threadIdx.x < st) {
      red[0][threadIdx.x] += red[0][threadIdx.x + st];
      red[1][threadIdx.x] += red[1][threadIdx.x + st];
    }
    __syncthreads();
  }
  if (threadIdx.x == 0) {
    pstat[((size_t)bs * NO + o) * 2] = red[0][0];
    pstat[((size_t)bs * NO + o) * 2 + 1] = red[1][0];
  }
}

// ------- per-o BN stats stage B: scl = g*rsqrt(var+eps) -------
__global__ void k_stats_o_fin(const float* __restrict__ pstat, const float* __restrict__ g,
                              float* __restrict__ scl) {
  int o = threadIdx.x;
  float s = 0.f, s2 = 0.f;
#pragma unroll
  for (int p = 0; p < 8; ++p) {
    s  += pstat[((size_t)p * NO + o) * 2];
    s2 += pstat[((size_t)p * NO + o) * 2 + 1];
  }
  float invN = 1.0f / (float)(NB * 64);
  float m = s * invN;
  float var = s2 * invN - m * m;
  scl[o] = g[o] * rsqrtf(var + 1e-5f);
}

// ---- pipelined bf16 GEMM, C[m][n] = sum_k A[m][k]*B[n][k] (B^T layout), split-K ----
// BM=BN=128, BK=32, 4 waves (2x2), ring-3 LDS K-tile slots (48KB):
//   per tile: ds_read frags -> lgkmcnt(0) -> barrier (slot free) ->
//   issue stage(tile j+3 -> slot j%3) -> setprio(1) 16 MFMA setprio(0) ->
//   vmcnt(8) (2 tiles in flight, tile j+1 landed) -> barrier.
// Loads stay in flight across barriers (T3/T4); tail = clamped dummy re-stages
// (issued after the reads-complete barrier, data identical or never read).
__global__ __launch_bounds__(256) void k_gemmp(const u16* __restrict__ A,
                                               const u16* __restrict__ B,
                                               float* __restrict__ C,
                                               int M, int N, int K, int ksz) {
  __shared__ u16 lds[3 * 8192];   // 3 slots x (A 128x32 + B 128x32) = 48KB
  const int tid = threadIdx.x, lane = tid & 63, wid = tid >> 6;
  const int wr = wid >> 1, wc = wid & 1;
  const int m0 = blockIdx.x * 128, n0 = blockIdx.y * 128;
  const int k0 = blockIdx.z * ksz;
  C += (size_t)blockIdx.z * ((size_t)M * N);

  f32x4 acc[4][4];
#pragma unroll
  for (int mi = 0; mi < 4; ++mi)
#pragma unroll
    for (int ni = 0; ni < 4; ++ni) acc[mi][ni] = (f32x4){0.f, 0.f, 0.f, 0.f};

  // staging: waves 0-1 -> A rows [wid*64,+64), waves 2-3 -> B rows [(wid-2)*64,+64)
  // per wave-issue: 16 rows x 64B = 1KB; 4 issues per wave per K-tile.
  const u16* gstage = (wid < 2)
      ? A + (size_t)(m0 + wid * 64 + (lane >> 2)) * K + k0 + (lane & 3) * 8
      : B + (size_t)(n0 + (wid - 2) * 64 + (lane >> 2)) * K + k0 + (lane & 3) * 8;
  const int lstage = (wid < 2) ? (wid * 64) * 32 : 4096 + ((wid - 2) * 64) * 32;

  const int la15 = lane & 15, la4 = lane >> 4;
  const u16* aoff = lds + (wr * 64 + la15) * 32 + la4 * 8;
  const u16* boff = lds + 4096 + (wc * 64 + la15) * 32 + la4 * 8;

  const int nkt = ksz / 32;
  // prologue: stage tiles 0,1,2 into slots 0,1,2
#pragma unroll
  for (int t = 0; t < 3; ++t)
#pragma unroll
    for (int i = 0; i < 4; ++i)
      GLOAD16(gstage + (size_t)t * 32 + (size_t)i * 16 * K, lds + t * 8192 + lstage + i * 512);
  asm volatile("s_waitcnt vmcnt(8)" ::: "memory");   // my tile-0 loads landed
  __builtin_amdgcn_sched_barrier(0);
  __builtin_amdgcn_s_barrier();                      // everyone's tile-0 landed
  __builtin_amdgcn_sched_barrier(0);

  int slot = 0;
  for (int j = 0; j < nkt; ++j) {
    bf16x8 af[4], bfv[4];
#pragma unroll
    for (int i = 0; i < 4; ++i) {
      af[i]  = *(const bf16x8*)(aoff + slot * 8192 + i * 512);
      bfv[i] = *(const bf16x8*)(boff + slot * 8192 + i * 512);
    }
    asm volatile("s_waitcnt lgkmcnt(0)" ::: "memory");  // my reads of slot complete
    __builtin_amdgcn_sched_barrier(0);
    __builtin_amdgcn_s_barrier();                       // all waves' reads complete
    __builtin_amdgcn_sched_barrier(0);
    const int ts = (j + 3 < nkt) ? j + 3 : nkt - 1;     // tail: benign dummy re-stage
#pragma unroll
    for (int i = 0; i < 4; ++i)
      GLOAD16(gstage + (size_t)ts * 32 + (size_t)i * 16 * K,
              lds + slot * 8192 + lstage + i * 512);
    __builtin_amdgcn_s_setprio(1);
#pragma unroll
    for (int mi = 0; mi < 4; ++mi)
#pragma unroll
      for (int ni = 0; ni < 4; ++ni)
        acc[mi][ni] = __builtin_amdgcn_mfma_f32_16x16x32_bf16(af[mi], bfv[ni], acc[mi][ni], 0, 0, 0);
    __builtin_amdgcn_s_setprio(0);
    asm volatile("s_waitcnt vmcnt(8)" ::: "memory");    // tile j+1 (mine) landed
    __builtin_amdgcn_sched_barrier(0);
    __builtin_amdgcn_s_barrier();                       // tile j+1 (everyone's) landed
    __builtin_amdgcn_sched_barrier(0);
    slot = (slot == 2) ? 0 : slot + 1;
  }

#pragma unroll
  for (int mi = 0; mi < 4; ++mi) {
    int m = m0 + wr * 64 + mi * 16 + ((lane >> 4) * 4);
#pragma unroll
    for (int ni = 0; ni < 4; ++ni) {
      int n = n0 + wc * 64 + ni * 16 + (lane & 15);
#pragma unroll
      for (int i = 0; i < 4; ++i) C[(size_t)(m + i) * N + n] = acc[mi][ni][i];
    }
  }
}

// ---- fused: r = sum of NP split-K partials  +  per-(rowgroup,col) BN partial stats ----
template <int NP>
__global__ void k_red_stats(const float* __restrict__ c, float* __restrict__ r,
                            float* __restrict__ pstat) {
  const int col = blockIdx.x * 64 + (threadIdx.x & 63);
  const int rt = threadIdx.x >> 6;
  const int rg = blockIdx.y;
  const size_t ps = (size_t)NB * 1024;
  float s = 0.f, s2 = 0.f;
  for (int rr = rt; rr < 64; rr += 4) {
    size_t idx = (size_t)(rg * 64 + rr) * 1024 + col;
    float v = c[idx];
#pragma unroll
    for (int p = 1; p < NP; ++p) v += c[p * ps + idx];
    r[idx] = v;
    s += v;
    s2 = fmaf(v, v, s2);
  }
  __shared__ float red[2][256];
  red[0][threadIdx.x] = s; red[1][threadIdx.x] = s2;
  __syncthreads();
  if (threadIdx.x < 64) {
    int t = threadIdx.x;
    s  = red[0][t] + red[0][t + 64] + red[0][t + 128] + red[0][t + 192];
    s2 = red[1][t] + red[1][t + 64] + red[1][t + 128] + red[1][t + 192];
    pstat[((size_t)rg * 1024 + col) * 2]     = s;
    pstat[((size_t)rg * 1024 + col) * 2 + 1] = s2;
  }
}

// ---- finalize col BN: fold 32 rowgroup partials -> scl/bia ----
__global__ void k_stats_fin(const float* __restrict__ pstat,
                            const float* __restrict__ g, const float* __restrict__ be,
                            float* __restrict__ scl, float* __restrict__ bia) {
  int col = blockIdx.x * 256 + threadIdx.x;
  float s = 0.f, s2 = 0.f;
#pragma unroll
  for (int p = 0; p < 32; ++p) {
    s  += pstat[((size_t)p * 1024 + col) * 2];
    s2 += pstat[((size_t)p * 1024 + col) * 2 + 1];
  }
  float invN = 1.0f / (float)NB;
  float m = s * invN;
  float var = s2 * invN - m * m;
  float inv = rsqrtf(var + 1e-5f);
  scl[col] = g[col] * inv;
  bia[col] = be[col] - g[col] * inv * m;
}

// ---------------- a1 = bf16(relu(r0*scl + bia)) ----------------
__global__ void k_applyA1(const float* __restrict__ c0,
                          const float* __restrict__ scl, const float* __restrict__ bia,
                          u16* __restrict__ a1) {
  size_t i4 = ((size_t)blockIdx.x * 256 + threadIdx.x) * 4;
  int n = (int)(i4 & 1023);
  float4 v0 = *(const float4*)(c0 + i4);
  ushort4 o;
  o.x = f2bf(fmaxf(fmaf(v0.x, scl[n + 0], bia[n + 0]), 0.f));
  o.y = f2bf(fmaxf(fmaf(v0.y, scl[n + 1], bia[n + 1]), 0.f));
  o.z = f2bf(fmaxf(fmaf(v0.z, scl[n + 2], bia[n + 2]), 0.f));
  o.w = f2bf(fmaxf(fmaf(v0.w, scl[n + 3], bia[n + 3]), 0.f));
  *(ushort4*)(a1 + i4) = o;
}

// -------- y[b] = out_b + sum_n relu(h*scl+bia)*out_w[n] --------
__global__ void k_final(const float* __restrict__ h, const float* __restrict__ scl,
                        const float* __restrict__ bia, const float* __restrict__ ow,
                        const float* __restrict__ ob, float* __restrict__ y) {
  int lane = threadIdx.x & 63, wid = threadIdx.x >> 6;
  int row = blockIdx.x * 4 + wid;
  const float* hr = h + (size_t)row * 1024;
  float part = 0.f;
#pragma unroll
  for (int j = 0; j < 16; ++j) {
    int n = j * 64 + lane;
    float v = fmaxf(fmaf(hr[n], scl[n], bia[n]), 0.f);
    part = fmaf(v, ow[n], part);
  }
#pragma unroll
  for (int off = 32; off >= 1; off >>= 1) part += __shfl_xor(part, off);
  if (lane == 0) y[row] = part + ob[0];
}

extern "C" void kernel_launch(void* const* d_in, const int* in_sizes, int n_in,
                              void* d_out, int out_size, void* d_ws, size_t ws_size,
                              hipStream_t stream) {
  const int*   ids   = (const int*)d_in[0];
  const float* vals  = (const float*)d_in[1];
  const float* etab  = (const float*)d_in[2];
  const float* wb    = (const float*)d_in[3];
  const float* query = (const float*)d_in[4];
  const float* att   = (const float*)d_in[5];
  const float* bng   = (const float*)d_in[6];
  const float* w0    = (const float*)d_in[8];
  const float* g0    = (const float*)d_in[10];
  const float* be0   = (const float*)d_in[11];
  const float* w1    = (const float*)d_in[12];
  const float* g1    = (const float*)d_in[14];
  const float* be1   = (const float*)d_in[15];
  const float* outw  = (const float*)d_in[16];
  const float* outb  = (const float*)d_in[17];
  float* y = (float*)d_out;

  // workspace layout (peak ~195.6 MB):
  //   [0, 32K)            mt
  //   [32K, 33.59M)       w0bf (32MB, pre-scaled by arm-BN scl)
  //   [33.59M, 35.68M)    w1bf (2MB)
  //   [35.68M, 102.79M)   tbuf (64MB bf16)  -- alive through gemm0 (A operand)
  //   [102.79M, 134.87M)  c01 (4x8MB f32)   -- gemm0 partials; dead after red_stats<4>
  //   [102.79M, 119.57M)  h1 (2x8MB f32)    -- overlays dead c01; gemm1 partials
  //   [169.90M, 178.29M)  r0 (8MB f32)
  //   [178.29M, 182.48M)  a1 (4MB bf16)
  //   [186.68M, 195.07M)  h (8MB f32, summed)
  //   [195.07M, ...)      pstat1/pstat2/pstatO + BN scalars
  char* ws = (char*)d_ws;
  u16*   mt     = (u16*)(ws + 0);
  u16*   w0bf   = (u16*)(ws + 32768ull);
  u16*   w1bf   = (u16*)(ws + 33587200ull);
  u16*   tbuf   = (u16*)(ws + 35684352ull);
  float* c01    = (float*)(ws + 102793216ull);
  float* h1     = (float*)(ws + 102793216ull);
  float* r0     = (float*)(ws + 169902080ull);
  u16*   a1     = (u16*)(ws + 178290688ull);
  float* h      = (float*)(ws + 186679296ull);
  float* pstat1 = (float*)(ws + 195067904ull);
  float* pstat2 = (float*)(ws + 195330048ull);
  float* pstatO = (float*)(ws + 195592192ull);
  float* sclA   = (float*)(ws + 195608576ull);
  float* scl1   = (float*)(ws + 195609600ull);
  float* bia1   = (float*)(ws + 195613696ull);
  float* scl2   = (float*)(ws + 195617792ull);
  float* bia2   = (float*)(ws + 195621888ull);

  k_prep_M<<<64, 256, 0, stream>>>(wb, query, mt);
  k_cvt<<<1024, 256, 0, stream>>>(w1, w1bf, 1024 * 1024);
  k_mega<<<2048, 256, 0, stream>>>(ids, vals, etab, mt, att, tbuf);
  k_stats_o_part<<<dim3(256, 8), 256, 0, stream>>>(tbuf, pstatO);
  k_stats_o_fin<<<1, 256, 0, stream>>>(pstatO, bng, sclA);
  k_cvt_w0s<<<16384, 256, 0, stream>>>(w0, sclA, w0bf);
  // gemm0: split-K=4 -> 512 blocks, ring-3 pipelined, ksz=4096 (nkt=128)
  k_gemmp<<<dim3(16, 8, 4), 256, 0, stream>>>(tbuf, w0bf, c01, 2048, 1024, 16384, 4096);
  k_red_stats<4><<<dim3(16, 32), 256, 0, stream>>>(c01, r0, pstat1);
  k_stats_fin<<<4, 256, 0, stream>>>(pstat1, g0, be0, scl1, bia1);
  k_applyA1<<<2048, 256, 0, stream>>>(r0, scl1, bia1, a1);
  // gemm1: split-K=2 -> 256 blocks, ksz=512 (nkt=16)
  k_gemmp<<<dim3(16, 8, 2), 256, 0, stream>>>(a1, w1bf, h1, 2048, 1024, 1024, 512);
  k_red_stats<2><<<dim3(16, 32), 256, 0, stream>>>(h1, h, pstat2);
  k_stats_fin<<<4, 256, 0, stream>>>(pstat2, g1, be1, scl2, bia2);
  k_final<<<512, 256, 0, stream>>>(h, scl2, bia2, outw, outb, y);
}

// Round 8
// 273.113 us; speedup vs baseline: 3.7460x; 1.0028x over previous
//
#include <hip/hip_runtime.h>

typedef unsigned short u16;
typedef __attribute__((ext_vector_type(8))) short bf16x8;
typedef __attribute__((ext_vector_type(8))) unsigned short u16x8;
typedef __attribute__((ext_vector_type(4))) float f32x4;

__device__ __forceinline__ u16 f2bf(float f) {
  unsigned u = __builtin_bit_cast(unsigned, f);
  u += 0x7fffu + ((u >> 16) & 1u);
  return (u16)(u >> 16);
}
__device__ __forceinline__ float bf2f(u16 h) {
  unsigned u = ((unsigned)h) << 16;
  return __builtin_bit_cast(float, u);
}

#define NB 2048
#define NF 100
#define NE 64
#define NO 256
#define OCH 64
#define EMB_ST 72
#define EMBT_ST 136
#define GAW_ST 136

#define GLOAD16(gsrc, ldst)                                                        \
  __builtin_amdgcn_global_load_lds(                                                \
      (const __attribute__((address_space(1))) unsigned int*)(gsrc),               \
      (__attribute__((address_space(3))) unsigned int*)(ldst), 16, 0, 0)

// ---------------- prep: M[o][e] = 0.0625 * sum_k query[o,k]*Wb[k,e] ----------------
__global__ void k_prep_M(const float* __restrict__ wb, const float* __restrict__ q,
                         u16* __restrict__ mt) {
  int idx = blockIdx.x * 256 + threadIdx.x;   // 16384 = 256*64
  int o = idx >> 6, e = idx & 63;
  float s = 0.f;
  for (int k = 0; k < 64; ++k) s = fmaf(q[o * 64 + k], wb[k * 64 + e], s);
  mt[idx] = f2bf(s * 0.0625f);   // folds DK^-0.5 (0.125) and (alpha-1) (0.5)
}

// ---------------- f32 -> bf16 conversion ----------------
__global__ void k_cvt(const float* __restrict__ in, u16* __restrict__ out, int n) {
  int i4 = (blockIdx.x * 256 + threadIdx.x) * 4;
  if (i4 >= n) return;
  float4 v = *(const float4*)(in + i4);
  ushort4 o;
  o.x = f2bf(v.x); o.y = f2bf(v.y); o.z = f2bf(v.z); o.w = f2bf(v.w);
  *(ushort4*)(out + i4) = o;
}

// ------- f32 -> bf16 with per-k scale: w0'[n][k] = bf16(w0[n][k] * scl[k>>6]) -------
__global__ void k_cvt_w0s(const float* __restrict__ in, const float* __restrict__ scl,
                          u16* __restrict__ out) {
  size_t i4 = ((size_t)blockIdx.x * 256 + threadIdx.x) * 4;
  int o = (int)((i4 >> 6) & 255);
  float sc = scl[o];
  float4 v = *(const float4*)(in + i4);
  ushort4 u;
  u.x = f2bf(v.x * sc); u.y = f2bf(v.y * sc);
  u.z = f2bf(v.z * sc); u.w = f2bf(v.w * sc);
  *(ushort4*)(out + i4) = u;
}

// ------- fused gather + (per-o-chunk: gates GEMM + entmax + arm GEMM + exp-1) -------
__global__ __launch_bounds__(256) void k_mega(
    const int* __restrict__ ids, const float* __restrict__ vals,
    const float* __restrict__ etab, const u16* __restrict__ mt,
    const float* __restrict__ att, u16* __restrict__ tbuf) {
  __shared__ u16 s_emb[112][EMB_ST];     // [f][e], rows 100..111 zero; stride 72 = aligned b128
  __shared__ u16 s_embT[64][EMBT_ST];    // [e][f], cols 100..135 zero
  __shared__ u16 s_gaw[64][GAW_ST];      // phase1-2: gates; phase2-3: p*att (quad-local alias)
  __shared__ float s_rs[64];             // per-row 1/sum(p), folded into phase-3 acc

  const int tid = threadIdx.x;
  const int lane = tid & 63;
  const int wid = tid >> 6;
  const int b = blockIdx.x;

  // phase 0: gather emb = emb_table[ids]*clip(v)  (once per b)
  for (int f = wid; f < NF; f += 4) {
    int id = ids[b * NF + f];
    float v = vals[b * NF + f];
    v = fminf(fmaxf(v, 0.001f), 1.0f);
    float ev = etab[(size_t)id * NE + lane] * v;
    u16 bf = f2bf(ev);
    s_emb[f][lane] = bf;
    s_embT[lane][f] = bf;
  }
  for (int i = tid; i < 12 * EMB_ST; i += 256) s_emb[100 + i / EMB_ST][i % EMB_ST] = 0;
  for (int i = tid; i < 64 * 36; i += 256) s_embT[i / 36][100 + i % 36] = 0;
  for (int i = tid; i < 64 * 24; i += 256) s_gaw[i / 24][112 + i % 24] = 0;
  __syncthreads();

  for (int oc = 0; oc < 4; ++oc) {
    const int obase = oc * OCH;
    bf16x8 amt[2];
#pragma unroll
    for (int kh = 0; kh < 2; ++kh)
      amt[kh] = *(const bf16x8*)(mt + ((obase + wid * 16 + (lane & 15)) * 64 +
                                       kh * 32 + ((lane >> 4) * 8)));

    // phase 1: gates[o][f] = M[o,:]·emb[f,:]
#pragma unroll
    for (int ft = 0; ft < 7; ++ft) {
      f32x4 acc = {0.f, 0.f, 0.f, 0.f};
#pragma unroll
      for (int kh = 0; kh < 2; ++kh) {
        bf16x8 bfr = *(const bf16x8*)&s_emb[ft * 16 + (lane & 15)][kh * 32 + ((lane >> 4) * 8)];
        acc = __builtin_amdgcn_mfma_f32_16x16x32_bf16(amt[kh], bfr, acc, 0, 0, 0);
      }
      int fc = ft * 16 + (lane & 15);
      if (fc < NF) {
#pragma unroll
        for (int i = 0; i < 4; ++i)
          s_gaw[wid * 16 + ((lane >> 4) * 4) + i][fc] = f2bf(acc[i]);
      }
    }
    __syncthreads();

    // phase 2: entmax(alpha=1.5), pure Newton x5 + rcp, quad (4 lanes) per o-row.
    // Newton from tau0=mx-1 is monotone on the convex decreasing
    // f(tau)=sum max(x-tau,0)^2-1; worst case (uniform 100) tau err 3e-4 after
    // 5 iters, and renormalization cancels the uniform component -> << bf16 ulp.
    {
      const int q = tid & 3;
      const int r = tid >> 2;
      const int og = obase + r;
      float x[28];
#pragma unroll
      for (int j = 0; j < 7; ++j) {
        ushort4 g = *(const ushort4*)&s_gaw[r][j * 16 + q * 4];
        x[j * 4 + 0] = bf2f(g.x); x[j * 4 + 1] = bf2f(g.y);
        x[j * 4 + 2] = bf2f(g.z); x[j * 4 + 3] = bf2f(g.w);
      }
      if (q > 0) { x[24] = -1e30f; x[25] = -1e30f; x[26] = -1e30f; x[27] = -1e30f; }
      float attv[28];
#pragma unroll
      for (int j = 0; j < 7; ++j) {
        if (j < 6 || q == 0) {
          float4 av = *(const float4*)(att + og * NF + j * 16 + q * 4);
          attv[j * 4 + 0] = av.x; attv[j * 4 + 1] = av.y;
          attv[j * 4 + 2] = av.z; attv[j * 4 + 3] = av.w;
        } else {
          attv[j * 4 + 0] = 0.f; attv[j * 4 + 1] = 0.f;
          attv[j * 4 + 2] = 0.f; attv[j * 4 + 3] = 0.f;
        }
      }
      float m0 = x[0], m1 = x[1];
#pragma unroll
      for (int j = 2; j < 28; j += 2) { m0 = fmaxf(m0, x[j]); m1 = fmaxf(m1, x[j + 1]); }
      float mx = fmaxf(m0, m1);
      mx = fmaxf(mx, __shfl_xor(mx, 1));
      mx = fmaxf(mx, __shfl_xor(mx, 2));
      float tau = mx - 1.0f;
#pragma unroll
      for (int it = 0; it < 5; ++it) {
        float s0 = 0.f, s1 = 0.f, t0 = 0.f, t1 = 0.f;
#pragma unroll
        for (int j = 0; j < 14; ++j) {
          float d0 = fmaxf(x[j] - tau, 0.f);
          float d1 = fmaxf(x[j + 14] - tau, 0.f);
          s0 = fmaf(d0, d0, s0); s1 = fmaf(d1, d1, s1);
          t0 += d0; t1 += d1;
        }
        float s = s0 + s1, sd = t0 + t1;
        s += __shfl_xor(s, 1);
        s += __shfl_xor(s, 2);
        sd += __shfl_xor(sd, 1);
        sd += __shfl_xor(sd, 2);
        float den = 2.0f * sd + 1e-30f;
        float inv;
        asm("v_rcp_f32 %0, %1" : "=v"(inv) : "v"(den));
        tau += (s - 1.0f) * inv;
      }
      float s0 = 0.f, s1 = 0.f;
#pragma unroll
      for (int j = 0; j < 14; ++j) {
        float d0 = fmaxf(x[j] - tau, 0.f);
        float d1 = fmaxf(x[j + 14] - tau, 0.f);
        x[j] = d0 * d0;
        x[j + 14] = d1 * d1;
        s0 += x[j]; s1 += x[j + 14];
      }
      float s = s0 + s1;
      s += __shfl_xor(s, 1);
      s += __shfl_xor(s, 2);
      if (q == 0) s_rs[r] = 1.0f / s;
#pragma unroll
      for (int j = 0; j < 7; ++j) {
        ushort4 w;
        w.x = f2bf(x[j * 4 + 0] * attv[j * 4 + 0]);
        w.y = f2bf(x[j * 4 + 1] * attv[j * 4 + 1]);
        w.z = f2bf(x[j * 4 + 2] * attv[j * 4 + 2]);
        w.w = f2bf(x[j * 4 + 3] * attv[j * 4 + 3]);
        *(ushort4*)&s_gaw[r][j * 16 + q * 4] = w;
      }
    }
    __syncthreads();

    // phase 3: arm[o][e] = rs[o] * sum_f aw[o][f]*emb[f][e];  store t = exp(arm)-1
    f32x4 acc[4] = {};
#pragma unroll
    for (int h = 0; h < 4; ++h) {
      bf16x8 afr = *(const bf16x8*)&s_gaw[wid * 16 + (lane & 15)][h * 32 + ((lane >> 4) * 8)];
#pragma unroll
      for (int et = 0; et < 4; ++et) {
        bf16x8 bfr = *(const bf16x8*)&s_embT[et * 16 + (lane & 15)][h * 32 + ((lane >> 4) * 8)];
        acc[et] = __builtin_amdgcn_mfma_f32_16x16x32_bf16(afr, bfr, acc[et], 0, 0, 0);
      }
    }
    const int rbase = wid * 16 + ((lane >> 4) * 4);
    float rs4[4];
#pragma unroll
    for (int i = 0; i < 4; ++i) rs4[i] = s_rs[rbase + i];
    size_t orow = (size_t)b * NO + obase + rbase;
#pragma unroll
    for (int et = 0; et < 4; ++et) {
      int e = et * 16 + (lane & 15);
#pragma unroll
      for (int i = 0; i < 4; ++i)
        tbuf[(orow + i) * 64 + e] = f2bf(__expf(acc[et][i] * rs4[i]) - 1.0f);
    }
    __syncthreads();   // protect s_gaw/s_rs for next oc
  }
}

// ------- per-o BN stats stage A: partial (s,s2) over a 256-batch slice -------
__global__ void k_stats_o_part(const u16* __restrict__ t, float* __restrict__ pstat) {
  const int o = blockIdx.x, bs = blockIdx.y;
  const int e = threadIdx.x & 63, bt = threadIdx.x >> 6;
  float s = 0.f, s2 = 0.f;
  for (int b = bs * 256 + bt; b < bs * 256 + 256; b += 4) {
    float v = bf2f(t[((size_t)b * NO + o) * 64 + e]);
    s += v;
    s2 = fmaf(v, v, s2);
  }
  __shared__ float red[2][256];
  red[0][threadIdx.x] = s; red[1][threadIdx.x] = s2;
  __syncthreads();
  for (int st = 128; st >= 1; st >>= 1) {
    if (threadIdx.x < st) {
      red[0][threadIdx.x] += red[0][threadIdx.x + st];
      red[1][threadIdx.x] += red[1][threadIdx.x + st];
    }
    __syncthreads();
  }
  if (threadIdx.x == 0) {
    pstat[((size_t)bs * NO + o) * 2] = red[0][0];
    pstat[((size_t)bs * NO + o) * 2 + 1] = red[1][0];
  }
}

// ------- per-o BN stats stage B: scl = g*rsqrt(var+eps) -------
__global__ void k_stats_o_fin(const float* __restrict__ pstat, const float* __restrict__ g,
                              float* __restrict__ scl) {
  int o = threadIdx.x;
  float s = 0.f, s2 = 0.f;
#pragma unroll
  for (int p = 0; p < 8; ++p) {
    s  += pstat[((size_t)p * NO + o) * 2];
    s2 += pstat[((size_t)p * NO + o) * 2 + 1];
  }
  float invN = 1.0f / (float)(NB * 64);
  float m = s * invN;
  float var = s2 * invN - m * m;
  scl[o] = g[o] * rsqrtf(var + 1e-5f);
}

// ---- pipelined bf16 GEMM, C[m][n] = sum_k A[m][k]*B[n][k] (B^T layout), split-K ----
// BM=BN=128, BK=32, 4 waves (2x2), ring-4 LDS K-tile slots (64KB, 2 blocks/CU):
//   per tile: ds_read frags -> lgkmcnt(0) -> barrier (slot free) ->
//   issue stage(tile j+4 -> slot j&3) -> setprio(1) 16 MFMA setprio(0) ->
//   vmcnt(12) (3 tiles in flight, tile j+1 landed) -> barrier.
// Lead time ~3.5 iters covers HBM latency. Requires nkt >= 4.
// XCD-chunked block swizzle: XCD x gets nwg/8 consecutive work items ->
// its 4 B-panels (4MB) stay hot in the XCD-private L2.
__global__ __launch_bounds__(256) void k_gemmp(const u16* __restrict__ A,
                                               const u16* __restrict__ B,
                                               float* __restrict__ C,
                                               int M, int N, int K, int ksz) {
  __shared__ u16 lds[4 * 8192];   // 4 slots x (A 128x32 + B 128x32) = 64KB
  const int tid = threadIdx.x, lane = tid & 63, wid = tid >> 6;
  const int wr = wid >> 1, wc = wid & 1;

  const int nx = gridDim.x, ny = gridDim.y;
  const int nwg = nx * ny * gridDim.z;
  int lin = blockIdx.x + nx * (blockIdx.y + ny * blockIdx.z);
  int swz = (lin & 7) * (nwg >> 3) + (lin >> 3);   // nwg % 8 == 0 (512 or 256)
  const int bx = swz % nx;
  const int byz = swz / nx;
  const int by = byz % ny, bz = byz / ny;

  const int m0 = bx * 128, n0 = by * 128;
  const int k0 = bz * ksz;
  C += (size_t)bz * ((size_t)M * N);

  f32x4 acc[4][4];
#pragma unroll
  for (int mi = 0; mi < 4; ++mi)
#pragma unroll
    for (int ni = 0; ni < 4; ++ni) acc[mi][ni] = (f32x4){0.f, 0.f, 0.f, 0.f};

  // staging: waves 0-1 -> A rows [wid*64,+64), waves 2-3 -> B rows [(wid-2)*64,+64)
  const u16* gstage = (wid < 2)
      ? A + (size_t)(m0 + wid * 64 + (lane >> 2)) * K + k0 + (lane & 3) * 8
      : B + (size_t)(n0 + (wid - 2) * 64 + (lane >> 2)) * K + k0 + (lane & 3) * 8;
  const int lstage = (wid < 2) ? (wid * 64) * 32 : 4096 + ((wid - 2) * 64) * 32;

  const int la15 = lane & 15, la4 = lane >> 4;
  const u16* aoff = lds + (wr * 64 + la15) * 32 + la4 * 8;
  const u16* boff = lds + 4096 + (wc * 64 + la15) * 32 + la4 * 8;

  const int nkt = ksz / 32;
  // prologue: stage tiles 0..3 into slots 0..3
#pragma unroll
  for (int t = 0; t < 4; ++t)
#pragma unroll
    for (int i = 0; i < 4; ++i)
      GLOAD16(gstage + (size_t)t * 32 + (size_t)i * 16 * K, lds + t * 8192 + lstage + i * 512);
  asm volatile("s_waitcnt vmcnt(12)" ::: "memory");   // my tile-0 loads landed
  __builtin_amdgcn_sched_barrier(0);
  __builtin_amdgcn_s_barrier();                       // everyone's tile-0 landed
  __builtin_amdgcn_sched_barrier(0);

  int slot = 0;
  for (int j = 0; j < nkt; ++j) {
    bf16x8 af[4], bfv[4];
#pragma unroll
    for (int i = 0; i < 4; ++i) {
      af[i]  = *(const bf16x8*)(aoff + slot * 8192 + i * 512);
      bfv[i] = *(const bf16x8*)(boff + slot * 8192 + i * 512);
    }
    asm volatile("s_waitcnt lgkmcnt(0)" ::: "memory");  // my reads of slot complete
    __builtin_amdgcn_sched_barrier(0);
    __builtin_amdgcn_s_barrier();                       // all waves' reads complete
    __builtin_amdgcn_sched_barrier(0);
    const int ts = (j + 4 < nkt) ? j + 4 : nkt - 1;     // tail: benign dummy re-stage
#pragma unroll
    for (int i = 0; i < 4; ++i)
      GLOAD16(gstage + (size_t)ts * 32 + (size_t)i * 16 * K,
              lds + slot * 8192 + lstage + i * 512);
    __builtin_amdgcn_s_setprio(1);
#pragma unroll
    for (int mi = 0; mi < 4; ++mi)
#pragma unroll
      for (int ni = 0; ni < 4; ++ni)
        acc[mi][ni] = __builtin_amdgcn_mfma_f32_16x16x32_bf16(af[mi], bfv[ni], acc[mi][ni], 0, 0, 0);
    __builtin_amdgcn_s_setprio(0);
    asm volatile("s_waitcnt vmcnt(12)" ::: "memory");   // tile j+1 (mine) landed
    __builtin_amdgcn_sched_barrier(0);
    __builtin_amdgcn_s_barrier();                       // tile j+1 (everyone's) landed
    __builtin_amdgcn_sched_barrier(0);
    slot = (slot + 1) & 3;
  }

#pragma unroll
  for (int mi = 0; mi < 4; ++mi) {
    int m = m0 + wr * 64 + mi * 16 + ((lane >> 4) * 4);
#pragma unroll
    for (int ni = 0; ni < 4; ++ni) {
      int n = n0 + wc * 64 + ni * 16 + (lane & 15);
#pragma unroll
      for (int i = 0; i < 4; ++i) C[(size_t)(m + i) * N + n] = acc[mi][ni][i];
    }
  }
}

// ---- fused: r = sum of NP split-K partials  +  per-(rowgroup,col) BN partial stats ----
template <int NP>
__global__ void k_red_stats(const float* __restrict__ c, float* __restrict__ r,
                            float* __restrict__ pstat) {
  const int col = blockIdx.x * 64 + (threadIdx.x & 63);
  const int rt = threadIdx.x >> 6;
  const int rg = blockIdx.y;
  const size_t ps = (size_t)NB * 1024;
  float s = 0.f, s2 = 0.f;
  for (int rr = rt; rr < 64; rr += 4) {
    size_t idx = (size_t)(rg * 64 + rr) * 1024 + col;
    float v = c[idx];
#pragma unroll
    for (int p = 1; p < NP; ++p) v += c[p * ps + idx];
    r[idx] = v;
    s += v;
    s2 = fmaf(v, v, s2);
  }
  __shared__ float red[2][256];
  red[0][threadIdx.x] = s; red[1][threadIdx.x] = s2;
  __syncthreads();
  if (threadIdx.x < 64) {
    int t = threadIdx.x;
    s  = red[0][t] + red[0][t + 64] + red[0][t + 128] + red[0][t + 192];
    s2 = red[1][t] + red[1][t + 64] + red[1][t + 128] + red[1][t + 192];
    pstat[((size_t)rg * 1024 + col) * 2]     = s;
    pstat[((size_t)rg * 1024 + col) * 2 + 1] = s2;
  }
}

// ---- finalize col BN: fold 32 rowgroup partials -> scl/bia ----
__global__ void k_stats_fin(const float* __restrict__ pstat,
                            const float* __restrict__ g, const float* __restrict__ be,
                            float* __restrict__ scl, float* __restrict__ bia) {
  int col = blockIdx.x * 256 + threadIdx.x;
  float s = 0.f, s2 = 0.f;
#pragma unroll
  for (int p = 0; p < 32; ++p) {
    s  += pstat[((size_t)p * 1024 + col) * 2];
    s2 += pstat[((size_t)p * 1024 + col) * 2 + 1];
  }
  float invN = 1.0f / (float)NB;
  float m = s * invN;
  float var = s2 * invN - m * m;
  float inv = rsqrtf(var + 1e-5f);
  scl[col] = g[col] * inv;
  bia[col] = be[col] - g[col] * inv * m;
}

// ---------------- a1 = bf16(relu(r0*scl + bia)) ----------------
__global__ void k_applyA1(const float* __restrict__ c0,
                          const float* __restrict__ scl, const float* __restrict__ bia,
                          u16* __restrict__ a1) {
  size_t i4 = ((size_t)blockIdx.x * 256 + threadIdx.x) * 4;
  int n = (int)(i4 & 1023);
  float4 v0 = *(const float4*)(c0 + i4);
  ushort4 o;
  o.x = f2bf(fmaxf(fmaf(v0.x, scl[n + 0], bia[n + 0]), 0.f));
  o.y = f2bf(fmaxf(fmaf(v0.y, scl[n + 1], bia[n + 1]), 0.f));
  o.z = f2bf(fmaxf(fmaf(v0.z, scl[n + 2], bia[n + 2]), 0.f));
  o.w = f2bf(fmaxf(fmaf(v0.w, scl[n + 3], bia[n + 3]), 0.f));
  *(ushort4*)(a1 + i4) = o;
}

// -------- y[b] = out_b + sum_n relu(h*scl+bia)*out_w[n] --------
__global__ void k_final(const float* __restrict__ h, const float* __restrict__ scl,
                        const float* __restrict__ bia, const float* __restrict__ ow,
                        const float* __restrict__ ob, float* __restrict__ y) {
  int lane = threadIdx.x & 63, wid = threadIdx.x >> 6;
  int row = blockIdx.x * 4 + wid;
  const float* hr = h + (size_t)row * 1024;
  float part = 0.f;
#pragma unroll
  for (int j = 0; j < 16; ++j) {
    int n = j * 64 + lane;
    float v = fmaxf(fmaf(hr[n], scl[n], bia[n]), 0.f);
    part = fmaf(v, ow[n], part);
  }
#pragma unroll
  for (int off = 32; off >= 1; off >>= 1) part += __shfl_xor(part, off);
  if (lane == 0) y[row] = part + ob[0];
}

extern "C" void kernel_launch(void* const* d_in, const int* in_sizes, int n_in,
                              void* d_out, int out_size, void* d_ws, size_t ws_size,
                              hipStream_t stream) {
  const int*   ids   = (const int*)d_in[0];
  const float* vals  = (const float*)d_in[1];
  const float* etab  = (const float*)d_in[2];
  const float* wb    = (const float*)d_in[3];
  const float* query = (const float*)d_in[4];
  const float* att   = (const float*)d_in[5];
  const float* bng   = (const float*)d_in[6];
  const float* w0    = (const float*)d_in[8];
  const float* g0    = (const float*)d_in[10];
  const float* be0   = (const float*)d_in[11];
  const float* w1    = (const float*)d_in[12];
  const float* g1    = (const float*)d_in[14];
  const float* be1   = (const float*)d_in[15];
  const float* outw  = (const float*)d_in[16];
  const float* outb  = (const float*)d_in[17];
  float* y = (float*)d_out;

  // workspace layout (peak ~195.6 MB):
  //   [0, 32K)            mt
  //   [32K, 33.59M)       w0bf (32MB, pre-scaled by arm-BN scl)
  //   [33.59M, 35.68M)    w1bf (2MB)
  //   [35.68M, 102.79M)   tbuf (64MB bf16)  -- alive through gemm0 (A operand)
  //   [102.79M, 134.87M)  c01 (4x8MB f32)   -- gemm0 partials; dead after red_stats<4>
  //   [102.79M, 134.87M)  h1 (4x8MB f32)    -- overlays dead c01; gemm1 partials
  //   [169.90M, 178.29M)  r0 (8MB f32)
  //   [178.29M, 182.48M)  a1 (4MB bf16)
  //   [186.68M, 195.07M)  h (8MB f32, summed)
  //   [195.07M, ...)      pstat1/pstat2/pstatO + BN scalars
  char* ws = (char*)d_ws;
  u16*   mt     = (u16*)(ws + 0);
  u16*   w0bf   = (u16*)(ws + 32768ull);
  u16*   w1bf   = (u16*)(ws + 33587200ull);
  u16*   tbuf   = (u16*)(ws + 35684352ull);
  float* c01    = (float*)(ws + 102793216ull);
  float* h1     = (float*)(ws + 102793216ull);
  float* r0     = (float*)(ws + 169902080ull);
  u16*   a1     = (u16*)(ws + 178290688ull);
  float* h      = (float*)(ws + 186679296ull);
  float* pstat1 = (float*)(ws + 195067904ull);
  float* pstat2 = (float*)(ws + 195330048ull);
  float* pstatO = (float*)(ws + 195592192ull);
  float* sclA   = (float*)(ws + 195608576ull);
  float* scl1   = (float*)(ws + 195609600ull);
  float* bia1   = (float*)(ws + 195613696ull);
  float* scl2   = (float*)(ws + 195617792ull);
  float* bia2   = (float*)(ws + 195621888ull);

  k_prep_M<<<64, 256, 0, stream>>>(wb, query, mt);
  k_cvt<<<1024, 256, 0, stream>>>(w1, w1bf, 1024 * 1024);
  k_mega<<<2048, 256, 0, stream>>>(ids, vals, etab, mt, att, tbuf);
  k_stats_o_part<<<dim3(256, 8), 256, 0, stream>>>(tbuf, pstatO);
  k_stats_o_fin<<<1, 256, 0, stream>>>(pstatO, bng, sclA);
  k_cvt_w0s<<<16384, 256, 0, stream>>>(w0, sclA, w0bf);
  // gemm0: split-K=4 -> 512 blocks (2/CU), ring-4 pipelined, ksz=4096 (nkt=128)
  k_gemmp<<<dim3(16, 8, 4), 256, 0, stream>>>(tbuf, w0bf, c01, 2048, 1024, 16384, 4096);
  k_red_stats<4><<<dim3(16, 32), 256, 0, stream>>>(c01, r0, pstat1);
  k_stats_fin<<<4, 256, 0, stream>>>(pstat1, g0, be0, scl1, bia1);
  k_applyA1<<<2048, 256, 0, stream>>>(r0, scl1, bia1, a1);
  // gemm1: split-K=4 -> 512 blocks (2/CU), ksz=256 (nkt=8)
  k_gemmp<<<dim3(16, 8, 4), 256, 0, stream>>>(a1, w1bf, h1, 2048, 1024, 1024, 256);
  k_red_stats<4><<<dim3(16, 32), 256, 0, stream>>>(h1, h, pstat2);
  k_stats_fin<<<4, 256, 0, stream>>>(pstat2, g1, be1, scl2, bia2);
  k_final<<<512, 256, 0, stream>>>(h, scl2, bia2, outw, outb, y);
}